// Round 1
// baseline (1452.634 us; speedup 1.0000x reference)
//
#include <hip/hip_runtime.h>

#define NN 100000
#define NE 1600000

// ---------------- CSR build ----------------

__global__ void count_kernel(const int* __restrict__ dst, int* __restrict__ cnt) {
    int e = blockIdx.x * blockDim.x + threadIdx.x;
    if (e < NE) atomicAdd(&cnt[dst[e]], 1);
}

__global__ void dinv_kernel(const int* __restrict__ cnt, float* __restrict__ dinv) {
    int i = blockIdx.x * blockDim.x + threadIdx.x;
    if (i < NN) dinv[i] = rsqrtf((float)cnt[i] + 1.0f);
}

// single-block exclusive scan over NN counts -> row_ptr[NN+1]
__global__ void scan_kernel(const int* __restrict__ cnt, int* __restrict__ row_ptr) {
    __shared__ int sums[1024];
    int t = threadIdx.x;
    const int CH = (NN + 1023) / 1024;  // 98
    int begin = t * CH;
    int end = begin + CH; if (end > NN) end = NN;
    int s = 0;
    for (int i = begin; i < end; ++i) s += cnt[i];
    sums[t] = s;
    __syncthreads();
    for (int ofs = 1; ofs < 1024; ofs <<= 1) {
        int v = (t >= ofs) ? sums[t - ofs] : 0;
        __syncthreads();
        sums[t] += v;
        __syncthreads();
    }
    int run = sums[t] - s;  // exclusive prefix for this chunk
    for (int i = begin; i < end; ++i) { row_ptr[i] = run; run += cnt[i]; }
    if (t == 1023) row_ptr[NN] = sums[1023];  // == NE
}

__global__ void scatter_kernel(const int* __restrict__ src, const int* __restrict__ dst,
                               int* __restrict__ cursor, int* __restrict__ col) {
    int e = blockIdx.x * blockDim.x + threadIdx.x;
    if (e < NE) {
        int p = atomicAdd(&cursor[dst[e]], 1);
        col[p] = src[e];
    }
}

// ---------------- per-layer kernels ----------------

// h[i,c] = dinv[i] * sum_k x[i,k] * W[k,c]
template<int IN, int OUT>
__global__ void mm_kernel(const float* __restrict__ x, const float* __restrict__ W,
                          const float* __restrict__ dinv, float* __restrict__ h) {
    __shared__ float Ws[IN * OUT];
    for (int i = threadIdx.x; i < IN * OUT; i += blockDim.x) Ws[i] = W[i];
    __syncthreads();
    int idx = blockIdx.x * blockDim.x + threadIdx.x;
    if (idx >= NN * OUT) return;
    int row = idx / OUT;          // OUT is power of 2 -> shift
    int c = idx & (OUT - 1);
    const float* xr = x + (size_t)row * IN;
    float sum = 0.f;
#pragma unroll
    for (int k = 0; k < IN; ++k) sum += xr[k] * Ws[k * OUT + c];
    h[idx] = dinv[row] * sum;
}

// out[i,c] = act( dinv[i] * (h[i,c] + sum_{j in in(i)} h[col[j],c]) + b[c] )
template<int OUT, bool RELU>
__global__ void agg_kernel(const float* __restrict__ h, const int* __restrict__ row_ptr,
                           const int* __restrict__ col, const float* __restrict__ dinv,
                           const float* __restrict__ b, float* __restrict__ out) {
    int idx = blockIdx.x * blockDim.x + threadIdx.x;
    if (idx >= NN * OUT) return;
    int node = idx / OUT;
    int c = idx & (OUT - 1);
    int beg = row_ptr[node];
    int end = row_ptr[node + 1];
    float sum = h[idx];  // self-loop contribution (already has one dinv factor)
    for (int j = beg; j < end; ++j) {
        int s = col[j];  // wave-uniform (broadcast) within the node's thread group
        sum += h[(size_t)s * OUT + c];
    }
    float v = dinv[node] * sum + b[c];
    if (RELU) v = fmaxf(v, 0.f);
    out[idx] = v;
}

// ---------------- launch ----------------

extern "C" void kernel_launch(void* const* d_in, const int* in_sizes, int n_in,
                              void* d_out, int out_size, void* d_ws, size_t ws_size,
                              hipStream_t stream) {
    const int* ei = (const int*)d_in[0];
    const int* src = ei;
    const int* dst = ei + NE;
    const float* emb = (const float*)d_in[1];
    const float* We1 = (const float*)d_in[2]; const float* be1 = (const float*)d_in[3];
    const float* We2 = (const float*)d_in[4]; const float* be2 = (const float*)d_in[5];
    const float* Wd1 = (const float*)d_in[6]; const float* bd1 = (const float*)d_in[7];
    const float* Wd2 = (const float*)d_in[8]; const float* bd2 = (const float*)d_in[9];

    float* outp  = (float*)d_out;
    float* recon = outp;                      // [NN*128]
    float* z     = outp + (size_t)NN * 128;   // [NN*32]

    char* ws = (char*)d_ws;
    size_t off = 0;
    auto alloc = [&](size_t bytes) {
        void* p = ws + off;
        off += (bytes + 255) & ~(size_t)255;
        return p;
    };
    int*   cnt     = (int*)  alloc((size_t)NN * 4);        // later reused as scatter cursor
    int*   row_ptr = (int*)  alloc((size_t)(NN + 1) * 4);
    int*   col     = (int*)  alloc((size_t)NE * 4);
    float* dinv    = (float*)alloc((size_t)NN * 4);
    float* bufA    = (float*)alloc((size_t)NN * 128 * 4);
    float* bufB    = (float*)alloc((size_t)NN * 64 * 4);
    (void)ws_size; (void)in_sizes; (void)n_in; (void)out_size;

    // --- CSR build (graph identical across all 4 layers) ---
    hipMemsetAsync(cnt, 0, (size_t)NN * 4, stream);
    count_kernel<<<(NE + 255) / 256, 256, 0, stream>>>(dst, cnt);
    dinv_kernel<<<(NN + 255) / 256, 256, 0, stream>>>(cnt, dinv);
    scan_kernel<<<1, 1024, 0, stream>>>(cnt, row_ptr);
    hipMemcpyAsync(cnt, row_ptr, (size_t)NN * 4, hipMemcpyDeviceToDevice, stream); // cursor = row_ptr copy
    scatter_kernel<<<(NE + 255) / 256, 256, 0, stream>>>(src, dst, cnt, col);

    // --- layer 1: emb[N,32] -> bufB[N,64], relu ---
    mm_kernel<32, 64><<<(NN * 64 + 255) / 256, 256, 0, stream>>>(emb, We1, dinv, bufA);
    agg_kernel<64, true><<<(NN * 64 + 255) / 256, 256, 0, stream>>>(bufA, row_ptr, col, dinv, be1, bufB);

    // --- layer 2: bufB[N,64] -> z[N,32], relu ---
    mm_kernel<64, 32><<<(NN * 32 + 255) / 256, 256, 0, stream>>>(bufB, We2, dinv, bufA);
    agg_kernel<32, true><<<(NN * 32 + 255) / 256, 256, 0, stream>>>(bufA, row_ptr, col, dinv, be2, z);

    // --- layer 3: z[N,32] -> bufB[N,64], relu ---
    mm_kernel<32, 64><<<(NN * 64 + 255) / 256, 256, 0, stream>>>(z, Wd1, dinv, bufA);
    agg_kernel<64, true><<<(NN * 64 + 255) / 256, 256, 0, stream>>>(bufA, row_ptr, col, dinv, bd1, bufB);

    // --- layer 4: bufB[N,64] -> recon[N,128], no relu ---
    mm_kernel<64, 128><<<(NN * 128 + 255) / 256, 256, 0, stream>>>(bufB, Wd2, dinv, bufA);
    agg_kernel<128, false><<<(NN * 128 + 255) / 256, 256, 0, stream>>>(bufA, row_ptr, col, dinv, bd2, recon);
}

// Round 2
// 754.260 us; speedup vs baseline: 1.9259x; 1.9259x over previous
//
#include <hip/hip_runtime.h>

#define NN 100000
#define NE 1600000

// ---------------- CSR build ----------------

__global__ void count_kernel(const int* __restrict__ dst, int* __restrict__ cnt) {
    int e = blockIdx.x * blockDim.x + threadIdx.x;
    if (e < NE) atomicAdd(&cnt[dst[e]], 1);
}

__global__ void dinv_kernel(const int* __restrict__ cnt, float* __restrict__ dinv) {
    int i = blockIdx.x * blockDim.x + threadIdx.x;
    if (i < NN) dinv[i] = rsqrtf((float)cnt[i] + 1.0f);
}

// single-block exclusive scan over NN counts -> row_ptr[NN+1]
__global__ void scan_kernel(const int* __restrict__ cnt, int* __restrict__ row_ptr) {
    __shared__ int sums[1024];
    int t = threadIdx.x;
    const int CH = (NN + 1023) / 1024;  // 98
    int begin = t * CH;
    int end = begin + CH; if (end > NN) end = NN;
    int s = 0;
    for (int i = begin; i < end; ++i) s += cnt[i];
    sums[t] = s;
    __syncthreads();
    for (int ofs = 1; ofs < 1024; ofs <<= 1) {
        int v = (t >= ofs) ? sums[t - ofs] : 0;
        __syncthreads();
        sums[t] += v;
        __syncthreads();
    }
    int run = sums[t] - s;  // exclusive prefix for this chunk
    for (int i = begin; i < end; ++i) { row_ptr[i] = run; run += cnt[i]; }
    if (t == 1023) row_ptr[NN] = sums[1023];  // == NE
}

__global__ void scatter_kernel(const int* __restrict__ src, const int* __restrict__ dst,
                               int* __restrict__ cursor, int* __restrict__ col) {
    int e = blockIdx.x * blockDim.x + threadIdx.x;
    if (e < NE) {
        int p = atomicAdd(&cursor[dst[e]], 1);
        col[p] = src[e];
    }
}

// ---------------- per-layer kernels ----------------

// h[i,c] = dinv[i] * sum_k x[i,k] * W[k,c]
// Block-tiled: NPB = 256/TPN nodes per block; x tile staged in LDS (+1 pad),
// W staged in LDS read as float4. Thread = (node, 4-channel group).
template<int IN, int OUT>
__global__ void mm_kernel(const float* __restrict__ x, const float* __restrict__ W,
                          const float* __restrict__ dinv, float* __restrict__ h) {
    constexpr int TPN = OUT / 4;       // threads per node
    constexpr int NPB = 256 / TPN;     // nodes per block (100000 % NPB == 0 for 8/16/32)
    constexpr int XP  = IN + 1;        // padded x-row stride (bank-conflict fix)
    __shared__ float4 Ws[IN * TPN];
    __shared__ float  xs[NPB * XP];

    int tid = threadIdx.x;
    const float4* W4 = (const float4*)W;
    for (int i = tid; i < IN * TPN; i += 256) Ws[i] = W4[i];

    int n0 = blockIdx.x * NPB;
    // coalesced x-tile load, scatter into padded LDS rows
    for (int i = tid; i < NPB * IN; i += 256) {
        int r = i / IN, cc = i & (IN - 1);
        xs[r * XP + cc] = x[(size_t)n0 * IN + i];
    }
    __syncthreads();

    int ln = tid / TPN;       // local node
    int cg = tid % TPN;       // channel group (4 channels)
    int node = n0 + ln;
    const float* xr = xs + ln * XP;

    float4 acc = {0.f, 0.f, 0.f, 0.f};
#pragma unroll
    for (int k = 0; k < IN; ++k) {
        float xv = xr[k];
        float4 w = Ws[k * TPN + cg];
        acc.x = fmaf(xv, w.x, acc.x);
        acc.y = fmaf(xv, w.y, acc.y);
        acc.z = fmaf(xv, w.z, acc.z);
        acc.w = fmaf(xv, w.w, acc.w);
    }
    float d = dinv[node];
    acc.x *= d; acc.y *= d; acc.z *= d; acc.w *= d;
    ((float4*)h)[(size_t)node * TPN + cg] = acc;
}

// out[i,c] = act( dinv[i] * (h[i,c] + sum_{j in in(i)} h[col[j],c]) + b[c] )
// Thread = (node, 4-channel group), float4 gather.
template<int OUT, bool RELU>
__global__ void agg_kernel(const float4* __restrict__ h, const int* __restrict__ row_ptr,
                           const int* __restrict__ col, const float* __restrict__ dinv,
                           const float* __restrict__ b, float4* __restrict__ out) {
    constexpr int TPN = OUT / 4;
    int gid = blockIdx.x * blockDim.x + threadIdx.x;
    int node = gid / TPN;
    int cg = gid % TPN;
    if (node >= NN) return;
    int beg = row_ptr[node];
    int end = row_ptr[node + 1];
    float4 sum = h[(size_t)node * TPN + cg];  // self-loop contribution
    for (int j = beg; j < end; ++j) {
        int s = col[j];  // wave-uniform within the node's thread group
        float4 v = h[(size_t)s * TPN + cg];
        sum.x += v.x; sum.y += v.y; sum.z += v.z; sum.w += v.w;
    }
    float d = dinv[node];
    float4 bb = ((const float4*)b)[cg];
    float4 r;
    r.x = fmaf(d, sum.x, bb.x);
    r.y = fmaf(d, sum.y, bb.y);
    r.z = fmaf(d, sum.z, bb.z);
    r.w = fmaf(d, sum.w, bb.w);
    if (RELU) {
        r.x = fmaxf(r.x, 0.f); r.y = fmaxf(r.y, 0.f);
        r.z = fmaxf(r.z, 0.f); r.w = fmaxf(r.w, 0.f);
    }
    out[(size_t)node * TPN + cg] = r;
}

// ---------------- launch ----------------

extern "C" void kernel_launch(void* const* d_in, const int* in_sizes, int n_in,
                              void* d_out, int out_size, void* d_ws, size_t ws_size,
                              hipStream_t stream) {
    const int* ei = (const int*)d_in[0];
    const int* src = ei;
    const int* dst = ei + NE;
    const float* emb = (const float*)d_in[1];
    const float* We1 = (const float*)d_in[2]; const float* be1 = (const float*)d_in[3];
    const float* We2 = (const float*)d_in[4]; const float* be2 = (const float*)d_in[5];
    const float* Wd1 = (const float*)d_in[6]; const float* bd1 = (const float*)d_in[7];
    const float* Wd2 = (const float*)d_in[8]; const float* bd2 = (const float*)d_in[9];

    float* outp  = (float*)d_out;
    float* recon = outp;                      // [NN*128]
    float* z     = outp + (size_t)NN * 128;   // [NN*32]

    char* ws = (char*)d_ws;
    size_t off = 0;
    auto alloc = [&](size_t bytes) {
        void* p = ws + off;
        off += (bytes + 255) & ~(size_t)255;
        return p;
    };
    int*   cnt     = (int*)  alloc((size_t)NN * 4);        // later reused as scatter cursor
    int*   row_ptr = (int*)  alloc((size_t)(NN + 1) * 4);
    int*   col     = (int*)  alloc((size_t)NE * 4);
    float* dinv    = (float*)alloc((size_t)NN * 4);
    float* bufA    = (float*)alloc((size_t)NN * 128 * 4);
    float* bufB    = (float*)alloc((size_t)NN * 64 * 4);
    (void)ws_size; (void)in_sizes; (void)n_in; (void)out_size;

    // --- CSR build (graph identical across all 4 layers) ---
    hipMemsetAsync(cnt, 0, (size_t)NN * 4, stream);
    count_kernel<<<(NE + 255) / 256, 256, 0, stream>>>(dst, cnt);
    dinv_kernel<<<(NN + 255) / 256, 256, 0, stream>>>(cnt, dinv);
    scan_kernel<<<1, 1024, 0, stream>>>(cnt, row_ptr);
    hipMemcpyAsync(cnt, row_ptr, (size_t)NN * 4, hipMemcpyDeviceToDevice, stream); // cursor = row_ptr copy
    scatter_kernel<<<(NE + 255) / 256, 256, 0, stream>>>(src, dst, cnt, col);

    // --- layer 1: emb[N,32] -> bufB[N,64], relu ---
    mm_kernel<32, 64><<<NN / 16, 256, 0, stream>>>(emb, We1, dinv, bufA);
    agg_kernel<64, true><<<(NN * 16 + 255) / 256, 256, 0, stream>>>(
        (const float4*)bufA, row_ptr, col, dinv, be1, (float4*)bufB);

    // --- layer 2: bufB[N,64] -> z[N,32], relu ---
    mm_kernel<64, 32><<<NN / 32, 256, 0, stream>>>(bufB, We2, dinv, bufA);
    agg_kernel<32, true><<<(NN * 8 + 255) / 256, 256, 0, stream>>>(
        (const float4*)bufA, row_ptr, col, dinv, be2, (float4*)z);

    // --- layer 3: z[N,32] -> bufB[N,64], relu ---
    mm_kernel<32, 64><<<NN / 16, 256, 0, stream>>>(z, Wd1, dinv, bufA);
    agg_kernel<64, true><<<(NN * 16 + 255) / 256, 256, 0, stream>>>(
        (const float4*)bufA, row_ptr, col, dinv, bd1, (float4*)bufB);

    // --- layer 4: bufB[N,64] -> recon[N,128], no relu ---
    mm_kernel<64, 128><<<NN / 8, 256, 0, stream>>>(bufB, Wd2, dinv, bufA);
    agg_kernel<128, false><<<(NN * 32 + 255) / 256, 256, 0, stream>>>(
        (const float4*)bufA, row_ptr, col, dinv, bd2, (float4*)recon);
}

// Round 3
// 602.131 us; speedup vs baseline: 2.4125x; 1.2527x over previous
//
#include <hip/hip_runtime.h>

#define NN 100000
#define NE 1600000
#define SCAN_NB 98   // ceil(NN / 1024)

// ---------------- CSR build ----------------

__global__ void count_kernel(const int* __restrict__ dst, int* __restrict__ cnt) {
    int e = blockIdx.x * blockDim.x + threadIdx.x;
    if (e < NE) atomicAdd(&cnt[dst[e]], 1);
}

// Phase 1: per-block exclusive scan of cnt into row_ptr (pre-offset), block sums,
// fused dinv = rsqrt(cnt+1). Each block covers 1024 elements (256 thr x int4).
__global__ void scan1_kernel(const int* __restrict__ cnt, int* __restrict__ row_ptr,
                             int* __restrict__ blkSum, float* __restrict__ dinv) {
    __shared__ int ts[256];
    int t = threadIdx.x, b = blockIdx.x;
    int base = b * 1024 + t * 4;          // NN % 4 == 0, so int4 is safe when base < NN
    int4 c = {0, 0, 0, 0};
    if (base < NN) {
        c = *(const int4*)(cnt + base);
        float4 dv = { rsqrtf((float)c.x + 1.f), rsqrtf((float)c.y + 1.f),
                      rsqrtf((float)c.z + 1.f), rsqrtf((float)c.w + 1.f) };
        *(float4*)(dinv + base) = dv;
    }
    int s = c.x + c.y + c.z + c.w;
    ts[t] = s;
    __syncthreads();
    for (int ofs = 1; ofs < 256; ofs <<= 1) {
        int v = (t >= ofs) ? ts[t - ofs] : 0;
        __syncthreads();
        ts[t] += v;
        __syncthreads();
    }
    if (t == 255) blkSum[b] = ts[255];
    int ex = ts[t] - s;   // exclusive prefix within block
    if (base < NN) {
        int4 p;
        p.x = ex; p.y = ex + c.x; p.z = p.y + c.y; p.w = p.z + c.z;
        *(int4*)(row_ptr + base) = p;
    }
}

// Phase 2: exclusive scan of the 98 block sums (single tiny block).
__global__ void scan2_kernel(int* __restrict__ blkSum) {
    __shared__ int ts[128];
    int t = threadIdx.x;
    int v = (t < SCAN_NB) ? blkSum[t] : 0;
    ts[t] = v;
    __syncthreads();
    for (int ofs = 1; ofs < 128; ofs <<= 1) {
        int u = (t >= ofs) ? ts[t - ofs] : 0;
        __syncthreads();
        ts[t] += u;
        __syncthreads();
    }
    if (t < SCAN_NB) blkSum[t] = ts[t] - v;  // exclusive
}

// Phase 3: add block offsets in place; emit final row_ptr AND scatter cursor.
__global__ void scan3_kernel(int* __restrict__ row_ptr, const int* __restrict__ blkSum,
                             int* __restrict__ cursor) {
    int b = blockIdx.x;
    int base = b * 1024 + threadIdx.x * 4;
    int off = blkSum[b];
    if (base < NN) {
        int4 p = *(const int4*)(row_ptr + base);
        p.x += off; p.y += off; p.z += off; p.w += off;
        *(int4*)(row_ptr + base) = p;
        *(int4*)(cursor + base) = p;
    }
    if (b == 0 && threadIdx.x == 0) row_ptr[NN] = NE;
}

__global__ void scatter_kernel(const int* __restrict__ src, const int* __restrict__ dst,
                               int* __restrict__ cursor, int* __restrict__ col) {
    int e = blockIdx.x * blockDim.x + threadIdx.x;
    if (e < NE) {
        int p = atomicAdd(&cursor[dst[e]], 1);
        col[p] = src[e];
    }
}

// ---------------- per-layer kernels ----------------

// h[i,c] = dinv[i] * sum_k x[i,k] * W[k,c]
template<int IN, int OUT>
__global__ void mm_kernel(const float* __restrict__ x, const float* __restrict__ W,
                          const float* __restrict__ dinv, float* __restrict__ h) {
    constexpr int TPN = OUT / 4;       // threads per node
    constexpr int NPB = 256 / TPN;     // nodes per block
    constexpr int XP  = IN + 1;        // padded x-row stride
    __shared__ float4 Ws[IN * TPN];
    __shared__ float  xs[NPB * XP];

    int tid = threadIdx.x;
    const float4* W4 = (const float4*)W;
    for (int i = tid; i < IN * TPN; i += 256) Ws[i] = W4[i];

    int n0 = blockIdx.x * NPB;
    for (int i = tid; i < NPB * IN; i += 256) {
        int r = i / IN, cc = i & (IN - 1);
        xs[r * XP + cc] = x[(size_t)n0 * IN + i];
    }
    __syncthreads();

    int ln = tid / TPN;
    int cg = tid % TPN;
    int node = n0 + ln;
    const float* xr = xs + ln * XP;

    float4 acc = {0.f, 0.f, 0.f, 0.f};
#pragma unroll
    for (int k = 0; k < IN; ++k) {
        float xv = xr[k];
        float4 w = Ws[k * TPN + cg];
        acc.x = fmaf(xv, w.x, acc.x);
        acc.y = fmaf(xv, w.y, acc.y);
        acc.z = fmaf(xv, w.z, acc.z);
        acc.w = fmaf(xv, w.w, acc.w);
    }
    float d = dinv[node];
    acc.x *= d; acc.y *= d; acc.z *= d; acc.w *= d;
    ((float4*)h)[(size_t)node * TPN + cg] = acc;
}

// out[i,c] = act( dinv[i] * (h[i,c] + sum_{j in in(i)} h[col[j],c]) + b[c] )
template<int OUT, bool RELU>
__global__ void agg_kernel(const float4* __restrict__ h, const int* __restrict__ row_ptr,
                           const int* __restrict__ col, const float* __restrict__ dinv,
                           const float* __restrict__ b, float4* __restrict__ out) {
    constexpr int TPN = OUT / 4;
    int gid = blockIdx.x * blockDim.x + threadIdx.x;
    int node = gid / TPN;
    int cg = gid % TPN;
    if (node >= NN) return;
    int beg = row_ptr[node];
    int end = row_ptr[node + 1];
    float4 sum = h[(size_t)node * TPN + cg];
    for (int j = beg; j < end; ++j) {
        int s = col[j];
        float4 v = h[(size_t)s * TPN + cg];
        sum.x += v.x; sum.y += v.y; sum.z += v.z; sum.w += v.w;
    }
    float d = dinv[node];
    float4 bb = ((const float4*)b)[cg];
    float4 r;
    r.x = fmaf(d, sum.x, bb.x);
    r.y = fmaf(d, sum.y, bb.y);
    r.z = fmaf(d, sum.z, bb.z);
    r.w = fmaf(d, sum.w, bb.w);
    if (RELU) {
        r.x = fmaxf(r.x, 0.f); r.y = fmaxf(r.y, 0.f);
        r.z = fmaxf(r.z, 0.f); r.w = fmaxf(r.w, 0.f);
    }
    out[(size_t)node * TPN + cg] = r;
}

// ---------------- launch ----------------

extern "C" void kernel_launch(void* const* d_in, const int* in_sizes, int n_in,
                              void* d_out, int out_size, void* d_ws, size_t ws_size,
                              hipStream_t stream) {
    const int* ei = (const int*)d_in[0];
    const int* src = ei;
    const int* dst = ei + NE;
    const float* emb = (const float*)d_in[1];
    const float* We1 = (const float*)d_in[2]; const float* be1 = (const float*)d_in[3];
    const float* We2 = (const float*)d_in[4]; const float* be2 = (const float*)d_in[5];
    const float* Wd1 = (const float*)d_in[6]; const float* bd1 = (const float*)d_in[7];
    const float* Wd2 = (const float*)d_in[8]; const float* bd2 = (const float*)d_in[9];

    float* outp  = (float*)d_out;
    float* recon = outp;                      // [NN*128]
    float* z     = outp + (size_t)NN * 128;   // [NN*32]

    char* ws = (char*)d_ws;
    size_t off = 0;
    auto alloc = [&](size_t bytes) {
        void* p = ws + off;
        off += (bytes + 255) & ~(size_t)255;
        return p;
    };
    int*   cnt     = (int*)  alloc((size_t)NN * 4);        // reused as scatter cursor
    int*   row_ptr = (int*)  alloc((size_t)(NN + 1) * 4);
    int*   col     = (int*)  alloc((size_t)NE * 4);
    float* dinv    = (float*)alloc((size_t)NN * 4);
    int*   blkSum  = (int*)  alloc((size_t)SCAN_NB * 4);
    float* bufA    = (float*)alloc((size_t)NN * 128 * 4);
    float* bufB    = (float*)alloc((size_t)NN * 64 * 4);
    (void)ws_size; (void)in_sizes; (void)n_in; (void)out_size;

    // --- CSR build ---
    hipMemsetAsync(cnt, 0, (size_t)NN * 4, stream);
    count_kernel<<<(NE + 255) / 256, 256, 0, stream>>>(dst, cnt);
    scan1_kernel<<<SCAN_NB, 256, 0, stream>>>(cnt, row_ptr, blkSum, dinv);
    scan2_kernel<<<1, 128, 0, stream>>>(blkSum);
    scan3_kernel<<<SCAN_NB, 256, 0, stream>>>(row_ptr, blkSum, cnt /* cursor */);
    scatter_kernel<<<(NE + 255) / 256, 256, 0, stream>>>(src, dst, cnt, col);

    // --- layer 1: emb[N,32] -> bufB[N,64], relu ---
    mm_kernel<32, 64><<<NN / 16, 256, 0, stream>>>(emb, We1, dinv, bufA);
    agg_kernel<64, true><<<(NN * 16 + 255) / 256, 256, 0, stream>>>(
        (const float4*)bufA, row_ptr, col, dinv, be1, (float4*)bufB);

    // --- layer 2: bufB[N,64] -> z[N,32], relu ---
    mm_kernel<64, 32><<<NN / 32, 256, 0, stream>>>(bufB, We2, dinv, bufA);
    agg_kernel<32, true><<<(NN * 8 + 255) / 256, 256, 0, stream>>>(
        (const float4*)bufA, row_ptr, col, dinv, be2, (float4*)z);

    // --- layer 3: z[N,32] -> bufB[N,64], relu ---
    mm_kernel<32, 64><<<NN / 16, 256, 0, stream>>>(z, Wd1, dinv, bufA);
    agg_kernel<64, true><<<(NN * 16 + 255) / 256, 256, 0, stream>>>(
        (const float4*)bufA, row_ptr, col, dinv, bd1, (float4*)bufB);

    // --- layer 4: bufB[N,64] -> recon[N,128], no relu ---
    mm_kernel<64, 128><<<NN / 8, 256, 0, stream>>>(bufB, Wd2, dinv, bufA);
    agg_kernel<128, false><<<(NN * 32 + 255) / 256, 256, 0, stream>>>(
        (const float4*)bufA, row_ptr, col, dinv, bd2, (float4*)recon);
}

// Round 4
// 547.892 us; speedup vs baseline: 2.6513x; 1.0990x over previous
//
#include <hip/hip_runtime.h>
#include <hip/hip_fp16.h>

#define NN 100000
#define NE 1600000
#define SCAN_NB 98   // ceil(NN / 1024)

// ---------------- CSR build ----------------

__global__ void count_kernel(const int* __restrict__ dst, int* __restrict__ cnt) {
    int e = blockIdx.x * blockDim.x + threadIdx.x;
    if (e < NE) atomicAdd(&cnt[dst[e]], 1);
}

// Phase 1: per-block exclusive scan of cnt into row_ptr (pre-offset), block sums,
// fused dinv = rsqrt(cnt+1). Each block covers 1024 elements (256 thr x int4).
__global__ void scan1_kernel(const int* __restrict__ cnt, int* __restrict__ row_ptr,
                             int* __restrict__ blkSum, float* __restrict__ dinv) {
    __shared__ int ts[256];
    int t = threadIdx.x, b = blockIdx.x;
    int base = b * 1024 + t * 4;
    int4 c = {0, 0, 0, 0};
    if (base < NN) {
        c = *(const int4*)(cnt + base);
        float4 dv = { rsqrtf((float)c.x + 1.f), rsqrtf((float)c.y + 1.f),
                      rsqrtf((float)c.z + 1.f), rsqrtf((float)c.w + 1.f) };
        *(float4*)(dinv + base) = dv;
    }
    int s = c.x + c.y + c.z + c.w;
    ts[t] = s;
    __syncthreads();
    for (int ofs = 1; ofs < 256; ofs <<= 1) {
        int v = (t >= ofs) ? ts[t - ofs] : 0;
        __syncthreads();
        ts[t] += v;
        __syncthreads();
    }
    if (t == 255) blkSum[b] = ts[255];
    int ex = ts[t] - s;
    if (base < NN) {
        int4 p;
        p.x = ex; p.y = ex + c.x; p.z = p.y + c.y; p.w = p.z + c.z;
        *(int4*)(row_ptr + base) = p;
    }
}

// Phase 2: exclusive scan of the 98 block sums (single tiny block).
__global__ void scan2_kernel(int* __restrict__ blkSum) {
    __shared__ int ts[128];
    int t = threadIdx.x;
    int v = (t < SCAN_NB) ? blkSum[t] : 0;
    ts[t] = v;
    __syncthreads();
    for (int ofs = 1; ofs < 128; ofs <<= 1) {
        int u = (t >= ofs) ? ts[t - ofs] : 0;
        __syncthreads();
        ts[t] += u;
        __syncthreads();
    }
    if (t < SCAN_NB) blkSum[t] = ts[t] - v;
}

// Phase 3: add block offsets in place; emit final row_ptr AND scatter cursor.
__global__ void scan3_kernel(int* __restrict__ row_ptr, const int* __restrict__ blkSum,
                             int* __restrict__ cursor) {
    int b = blockIdx.x;
    int base = b * 1024 + threadIdx.x * 4;
    int off = blkSum[b];
    if (base < NN) {
        int4 p = *(const int4*)(row_ptr + base);
        p.x += off; p.y += off; p.z += off; p.w += off;
        *(int4*)(row_ptr + base) = p;
        *(int4*)(cursor + base) = p;
    }
    if (b == 0 && threadIdx.x == 0) row_ptr[NN] = NE;
}

__global__ void scatter_kernel(const int* __restrict__ src, const int* __restrict__ dst,
                               int* __restrict__ cursor, int* __restrict__ col) {
    int e = blockIdx.x * blockDim.x + threadIdx.x;
    if (e < NE) {
        int p = atomicAdd(&cursor[dst[e]], 1);
        col[p] = src[e];
    }
}

// ---------------- per-layer kernels ----------------

__device__ inline float4 h4_to_f4(ushort4 u) {
    float4 r;
    r.x = __half2float(__ushort_as_half(u.x));
    r.y = __half2float(__ushort_as_half(u.y));
    r.z = __half2float(__ushort_as_half(u.z));
    r.w = __half2float(__ushort_as_half(u.w));
    return r;
}

// h[i,c] = fp16( dinv[i] * sum_k x[i,k] * W[k,c] )
template<int IN, int OUT>
__global__ void mm_kernel(const float* __restrict__ x, const float* __restrict__ W,
                          const float* __restrict__ dinv, ushort4* __restrict__ h) {
    constexpr int TPN = OUT / 4;       // threads per node
    constexpr int NPB = 256 / TPN;     // nodes per block
    constexpr int XP  = IN + 1;        // padded x-row stride
    __shared__ float4 Ws[IN * TPN];
    __shared__ float  xs[NPB * XP];

    int tid = threadIdx.x;
    const float4* W4 = (const float4*)W;
    for (int i = tid; i < IN * TPN; i += 256) Ws[i] = W4[i];

    int n0 = blockIdx.x * NPB;
    for (int i = tid; i < NPB * IN; i += 256) {
        int r = i / IN, cc = i & (IN - 1);
        xs[r * XP + cc] = x[(size_t)n0 * IN + i];
    }
    __syncthreads();

    int ln = tid / TPN;
    int cg = tid % TPN;
    int node = n0 + ln;
    const float* xr = xs + ln * XP;

    float4 acc = {0.f, 0.f, 0.f, 0.f};
#pragma unroll
    for (int k = 0; k < IN; ++k) {
        float xv = xr[k];
        float4 w = Ws[k * TPN + cg];
        acc.x = fmaf(xv, w.x, acc.x);
        acc.y = fmaf(xv, w.y, acc.y);
        acc.z = fmaf(xv, w.z, acc.z);
        acc.w = fmaf(xv, w.w, acc.w);
    }
    float d = dinv[node];
    ushort4 o;
    o.x = __half_as_ushort(__float2half(acc.x * d));
    o.y = __half_as_ushort(__float2half(acc.y * d));
    o.z = __half_as_ushort(__float2half(acc.z * d));
    o.w = __half_as_ushort(__float2half(acc.w * d));
    h[(size_t)node * TPN + cg] = o;
}

// out[i,c] = act( dinv[i] * (h[i,c] + sum_{j in in(i)} h[col[j],c]) + b[c] )
// Gather operand is fp16; accumulation f32.
template<int OUT, bool RELU>
__global__ void agg_kernel(const ushort4* __restrict__ h, const int* __restrict__ row_ptr,
                           const int* __restrict__ col, const float* __restrict__ dinv,
                           const float* __restrict__ b, float4* __restrict__ out) {
    constexpr int TPN = OUT / 4;
    int gid = blockIdx.x * blockDim.x + threadIdx.x;
    int node = gid / TPN;
    int cg = gid % TPN;
    if (node >= NN) return;
    int beg = row_ptr[node];
    int end = row_ptr[node + 1];
    float4 sum = h4_to_f4(h[(size_t)node * TPN + cg]);  // self-loop contribution
    for (int j = beg; j < end; ++j) {
        int s = col[j];
        float4 v = h4_to_f4(h[(size_t)s * TPN + cg]);
        sum.x += v.x; sum.y += v.y; sum.z += v.z; sum.w += v.w;
    }
    float d = dinv[node];
    float4 bb = ((const float4*)b)[cg];
    float4 r;
    r.x = fmaf(d, sum.x, bb.x);
    r.y = fmaf(d, sum.y, bb.y);
    r.z = fmaf(d, sum.z, bb.z);
    r.w = fmaf(d, sum.w, bb.w);
    if (RELU) {
        r.x = fmaxf(r.x, 0.f); r.y = fmaxf(r.y, 0.f);
        r.z = fmaxf(r.z, 0.f); r.w = fmaxf(r.w, 0.f);
    }
    out[(size_t)node * TPN + cg] = r;
}

// ---------------- launch ----------------

extern "C" void kernel_launch(void* const* d_in, const int* in_sizes, int n_in,
                              void* d_out, int out_size, void* d_ws, size_t ws_size,
                              hipStream_t stream) {
    const int* ei = (const int*)d_in[0];
    const int* src = ei;
    const int* dst = ei + NE;
    const float* emb = (const float*)d_in[1];
    const float* We1 = (const float*)d_in[2]; const float* be1 = (const float*)d_in[3];
    const float* We2 = (const float*)d_in[4]; const float* be2 = (const float*)d_in[5];
    const float* Wd1 = (const float*)d_in[6]; const float* bd1 = (const float*)d_in[7];
    const float* Wd2 = (const float*)d_in[8]; const float* bd2 = (const float*)d_in[9];

    float* outp  = (float*)d_out;
    float* recon = outp;                      // [NN*128]
    float* z     = outp + (size_t)NN * 128;   // [NN*32]

    char* ws = (char*)d_ws;
    size_t off = 0;
    auto alloc = [&](size_t bytes) {
        void* p = ws + off;
        off += (bytes + 255) & ~(size_t)255;
        return p;
    };
    int*     cnt     = (int*)    alloc((size_t)NN * 4);   // reused as scatter cursor
    int*     row_ptr = (int*)    alloc((size_t)(NN + 1) * 4);
    int*     col     = (int*)    alloc((size_t)NE * 4);
    float*   dinv    = (float*)  alloc((size_t)NN * 4);
    int*     blkSum  = (int*)    alloc((size_t)SCAN_NB * 4);
    ushort4* hbuf    = (ushort4*)alloc((size_t)NN * 128 * 2);  // fp16 h, max width 128
    float*   bufB    = (float*)  alloc((size_t)NN * 64 * 4);
    (void)ws_size; (void)in_sizes; (void)n_in; (void)out_size;

    // --- CSR build ---
    hipMemsetAsync(cnt, 0, (size_t)NN * 4, stream);
    count_kernel<<<(NE + 255) / 256, 256, 0, stream>>>(dst, cnt);
    scan1_kernel<<<SCAN_NB, 256, 0, stream>>>(cnt, row_ptr, blkSum, dinv);
    scan2_kernel<<<1, 128, 0, stream>>>(blkSum);
    scan3_kernel<<<SCAN_NB, 256, 0, stream>>>(row_ptr, blkSum, cnt /* cursor */);
    scatter_kernel<<<(NE + 255) / 256, 256, 0, stream>>>(src, dst, cnt, col);

    // --- layer 1: emb[N,32] -> bufB[N,64], relu ---
    mm_kernel<32, 64><<<NN / 16, 256, 0, stream>>>(emb, We1, dinv, hbuf);
    agg_kernel<64, true><<<(NN * 16 + 255) / 256, 256, 0, stream>>>(
        hbuf, row_ptr, col, dinv, be1, (float4*)bufB);

    // --- layer 2: bufB[N,64] -> z[N,32], relu ---
    mm_kernel<64, 32><<<NN / 32, 256, 0, stream>>>(bufB, We2, dinv, hbuf);
    agg_kernel<32, true><<<(NN * 8 + 255) / 256, 256, 0, stream>>>(
        hbuf, row_ptr, col, dinv, be2, (float4*)z);

    // --- layer 3: z[N,32] -> bufB[N,64], relu ---
    mm_kernel<32, 64><<<NN / 16, 256, 0, stream>>>(z, Wd1, dinv, hbuf);
    agg_kernel<64, true><<<(NN * 16 + 255) / 256, 256, 0, stream>>>(
        hbuf, row_ptr, col, dinv, bd1, (float4*)bufB);

    // --- layer 4: bufB[N,64] -> recon[N,128], no relu ---
    mm_kernel<64, 128><<<NN / 8, 256, 0, stream>>>(bufB, Wd2, dinv, hbuf);
    agg_kernel<128, false><<<(NN * 32 + 255) / 256, 256, 0, stream>>>(
        hbuf, row_ptr, col, dinv, bd2, (float4*)recon);
}

// Round 5
// 404.101 us; speedup vs baseline: 3.5947x; 1.3558x over previous
//
#include <hip/hip_runtime.h>
#include <hip/hip_fp16.h>

#define NN 100000
#define NE 1600000
#define NB 782            // dst buckets of 128 nodes: ceil(NN/128)
#define EPB 8192          // edges per block in bucket phases
#define NBLK_A 196        // ceil(NE/EPB)
#define SCNT (NB * NBLK_A)             // 153272 (divisible by 4)
#define SC_NB ((SCNT + 1023) / 1024)   // 150
#define CAP 4096          // bucket capacity for LDS staging (mean 2046, sd ~45)

// ---------------- CSR build: atomic-light bucketing ----------------

// Phase A: per-block histogram over NB buckets (LDS atomics only), transposed out.
__global__ void bhistA_kernel(const int* __restrict__ dst, int* __restrict__ histT) {
    __shared__ int hist[NB];
    int t = threadIdx.x, b = blockIdx.x;
    for (int i = t; i < NB; i += 256) hist[i] = 0;
    __syncthreads();
    int e0 = b * EPB;
    for (int i = t; i < EPB; i += 256) {
        int e = e0 + i;
        if (e < NE) atomicAdd(&hist[dst[e] >> 7], 1);
    }
    __syncthreads();
    for (int i = t; i < NB; i += 256) histT[i * NBLK_A + b] = hist[i];
}

// Generic 3-phase exclusive scan over SCNT ints.
__global__ void scan1g_kernel(const int* __restrict__ in, int* __restrict__ out,
                              int* __restrict__ blkSum) {
    __shared__ int ts[256];
    int t = threadIdx.x, b = blockIdx.x;
    int base = b * 1024 + t * 4;
    int4 c = {0, 0, 0, 0};
    if (base < SCNT) c = *(const int4*)(in + base);
    int s = c.x + c.y + c.z + c.w;
    ts[t] = s;
    __syncthreads();
    for (int ofs = 1; ofs < 256; ofs <<= 1) {
        int v = (t >= ofs) ? ts[t - ofs] : 0;
        __syncthreads();
        ts[t] += v;
        __syncthreads();
    }
    if (t == 255) blkSum[b] = ts[255];
    int ex = ts[t] - s;
    if (base < SCNT) {
        int4 p;
        p.x = ex; p.y = ex + c.x; p.z = p.y + c.y; p.w = p.z + c.z;
        *(int4*)(out + base) = p;
    }
}

__global__ void scan2g_kernel(int* __restrict__ blkSum) {  // SC_NB <= 256
    __shared__ int ts[256];
    int t = threadIdx.x;
    int v = (t < SC_NB) ? blkSum[t] : 0;
    ts[t] = v;
    __syncthreads();
    for (int ofs = 1; ofs < 256; ofs <<= 1) {
        int u = (t >= ofs) ? ts[t - ofs] : 0;
        __syncthreads();
        ts[t] += u;
        __syncthreads();
    }
    if (t < SC_NB) blkSum[t] = ts[t] - v;
}

__global__ void scan3g_kernel(int* __restrict__ out, const int* __restrict__ blkSum) {
    int b = blockIdx.x;
    int base = b * 1024 + threadIdx.x * 4;
    int off = blkSum[b];
    if (base < SCNT) {
        int4 p = *(const int4*)(out + base);
        p.x += off; p.y += off; p.z += off; p.w += off;
        *(int4*)(out + base) = p;
    }
}

// Phase B: scatter (src,dst) into bucket segments; cursors are per-(block,bucket)
// pre-scanned offsets held in LDS -> no global atomics, line-dense writes.
__global__ void bscatB_kernel(const int* __restrict__ src, const int* __restrict__ dst,
                              const int* __restrict__ scanT, int2* __restrict__ ebuf) {
    __shared__ int cur[NB];
    int t = threadIdx.x, b = blockIdx.x;
    for (int i = t; i < NB; i += 256) cur[i] = scanT[i * NBLK_A + b];
    __syncthreads();
    int e0 = b * EPB;
    for (int i = t; i < EPB; i += 256) {
        int e = e0 + i;
        if (e < NE) {
            int d = dst[e];
            int p = atomicAdd(&cur[d >> 7], 1);  // LDS atomic
            ebuf[p] = make_int2(src[e], d);
        }
    }
}

// Phase C: per-bucket CSR finalize. Stage bucket edges in LDS, 128-bin local
// histogram + scan -> contiguous col writes, row_ptr, fused dinv.
__global__ void csrC_kernel(const int2* __restrict__ ebuf, const int* __restrict__ scanT,
                            int* __restrict__ row_ptr, int* __restrict__ col,
                            float* __restrict__ dinv) {
    __shared__ int2 es[CAP];
    __shared__ int hist[128];
    __shared__ int ts[128];
    __shared__ int cur[128];
    int t = threadIdx.x, b = blockIdx.x;
    int base = scanT[b * NBLK_A];
    int end  = (b + 1 < NB) ? scanT[(b + 1) * NBLK_A] : NE;
    int cnt = end - base;
    if (t < 128) hist[t] = 0;
    __syncthreads();
    for (int i = t; i < cnt; i += 256) {
        int2 e = ebuf[base + i];
        if (i < CAP) es[i] = e;
        atomicAdd(&hist[e.y & 127], 1);
    }
    __syncthreads();
    if (t < 128) ts[t] = hist[t];
    __syncthreads();
    for (int ofs = 1; ofs < 128; ofs <<= 1) {
        int v = 0;
        if (t < 128 && t >= ofs) v = ts[t - ofs];
        __syncthreads();
        if (t < 128) ts[t] += v;
        __syncthreads();
    }
    if (t < 128) {
        int ex = ts[t] - hist[t];      // exclusive local base
        cur[t] = ex;
        int g = b * 128 + t;
        if (g < NN) {
            row_ptr[g] = base + ex;
            dinv[g] = rsqrtf((float)hist[t] + 1.0f);
        }
    }
    if (b == 0 && t == 0) row_ptr[NN] = NE;
    __syncthreads();
    for (int i = t; i < cnt; i += 256) {
        int2 e = (i < CAP) ? es[i] : ebuf[base + i];
        int r = atomicAdd(&cur[e.y & 127], 1);  // LDS atomic
        col[base + r] = e.x;
    }
}

// ---------------- per-layer kernels ----------------

__device__ inline float4 h4_to_f4(ushort4 u) {
    float4 r;
    r.x = __half2float(__ushort_as_half(u.x));
    r.y = __half2float(__ushort_as_half(u.y));
    r.z = __half2float(__ushort_as_half(u.z));
    r.w = __half2float(__ushort_as_half(u.w));
    return r;
}

// h[i,c] = fp16( dinv[i] * sum_k x[i,k] * W[k,c] )
template<int IN, int OUT>
__global__ void mm_kernel(const float* __restrict__ x, const float* __restrict__ W,
                          const float* __restrict__ dinv, ushort4* __restrict__ h) {
    constexpr int TPN = OUT / 4;
    constexpr int NPB = 256 / TPN;
    constexpr int XP  = IN + 1;
    __shared__ float4 Ws[IN * TPN];
    __shared__ float  xs[NPB * XP];

    int tid = threadIdx.x;
    const float4* W4 = (const float4*)W;
    for (int i = tid; i < IN * TPN; i += 256) Ws[i] = W4[i];

    int n0 = blockIdx.x * NPB;
    for (int i = tid; i < NPB * IN; i += 256) {
        int r = i / IN, cc = i & (IN - 1);
        xs[r * XP + cc] = x[(size_t)n0 * IN + i];
    }
    __syncthreads();

    int ln = tid / TPN;
    int cg = tid % TPN;
    int node = n0 + ln;
    const float* xr = xs + ln * XP;

    float4 acc = {0.f, 0.f, 0.f, 0.f};
#pragma unroll
    for (int k = 0; k < IN; ++k) {
        float xv = xr[k];
        float4 w = Ws[k * TPN + cg];
        acc.x = fmaf(xv, w.x, acc.x);
        acc.y = fmaf(xv, w.y, acc.y);
        acc.z = fmaf(xv, w.z, acc.z);
        acc.w = fmaf(xv, w.w, acc.w);
    }
    float d = dinv[node];
    ushort4 o;
    o.x = __half_as_ushort(__float2half(acc.x * d));
    o.y = __half_as_ushort(__float2half(acc.y * d));
    o.z = __half_as_ushort(__float2half(acc.z * d));
    o.w = __half_as_ushort(__float2half(acc.w * d));
    h[(size_t)node * TPN + cg] = o;
}

// out[i,c] = act( dinv[i] * (h[i,c] + sum_{j in in(i)} h[col[j],c]) + b[c] )
template<int OUT, bool RELU>
__global__ void agg_kernel(const ushort4* __restrict__ h, const int* __restrict__ row_ptr,
                           const int* __restrict__ col, const float* __restrict__ dinv,
                           const float* __restrict__ b, float4* __restrict__ out) {
    constexpr int TPN = OUT / 4;
    int gid = blockIdx.x * blockDim.x + threadIdx.x;
    int node = gid / TPN;
    int cg = gid % TPN;
    if (node >= NN) return;
    int beg = row_ptr[node];
    int end = row_ptr[node + 1];
    float4 sum = h4_to_f4(h[(size_t)node * TPN + cg]);
    for (int j = beg; j < end; ++j) {
        int s = col[j];
        float4 v = h4_to_f4(h[(size_t)s * TPN + cg]);
        sum.x += v.x; sum.y += v.y; sum.z += v.z; sum.w += v.w;
    }
    float d = dinv[node];
    float4 bb = ((const float4*)b)[cg];
    float4 r;
    r.x = fmaf(d, sum.x, bb.x);
    r.y = fmaf(d, sum.y, bb.y);
    r.z = fmaf(d, sum.z, bb.z);
    r.w = fmaf(d, sum.w, bb.w);
    if (RELU) {
        r.x = fmaxf(r.x, 0.f); r.y = fmaxf(r.y, 0.f);
        r.z = fmaxf(r.z, 0.f); r.w = fmaxf(r.w, 0.f);
    }
    out[(size_t)node * TPN + cg] = r;
}

// ---------------- launch ----------------

extern "C" void kernel_launch(void* const* d_in, const int* in_sizes, int n_in,
                              void* d_out, int out_size, void* d_ws, size_t ws_size,
                              hipStream_t stream) {
    const int* ei = (const int*)d_in[0];
    const int* src = ei;
    const int* dst = ei + NE;
    const float* emb = (const float*)d_in[1];
    const float* We1 = (const float*)d_in[2]; const float* be1 = (const float*)d_in[3];
    const float* We2 = (const float*)d_in[4]; const float* be2 = (const float*)d_in[5];
    const float* Wd1 = (const float*)d_in[6]; const float* bd1 = (const float*)d_in[7];
    const float* Wd2 = (const float*)d_in[8]; const float* bd2 = (const float*)d_in[9];

    float* outp  = (float*)d_out;
    float* recon = outp;                      // [NN*128]
    float* z     = outp + (size_t)NN * 128;   // [NN*32]

    char* ws = (char*)d_ws;
    size_t off = 0;
    auto alloc = [&](size_t bytes) {
        void* p = ws + off;
        off += (bytes + 255) & ~(size_t)255;
        return p;
    };
    int*     row_ptr = (int*)    alloc((size_t)(NN + 1) * 4);
    int*     col     = (int*)    alloc((size_t)NE * 4);
    float*   dinv    = (float*)  alloc((size_t)NN * 4);
    int*     histT   = (int*)    alloc((size_t)SCNT * 4);
    int*     scanT   = (int*)    alloc((size_t)SCNT * 4);
    int*     blkSum  = (int*)    alloc((size_t)SC_NB * 4);
    int2*    ebuf    = (int2*)   alloc((size_t)NE * 8);
    ushort4* hbuf    = (ushort4*)alloc((size_t)NN * 128 * 2);  // fp16 h, max width 128
    float*   bufB    = (float*)  alloc((size_t)NN * 64 * 4);
    (void)ws_size; (void)in_sizes; (void)n_in; (void)out_size;

    // --- CSR build (bucketed, no global atomics) ---
    bhistA_kernel<<<NBLK_A, 256, 0, stream>>>(dst, histT);
    scan1g_kernel<<<SC_NB, 256, 0, stream>>>(histT, scanT, blkSum);
    scan2g_kernel<<<1, 256, 0, stream>>>(blkSum);
    scan3g_kernel<<<SC_NB, 256, 0, stream>>>(scanT, blkSum);
    bscatB_kernel<<<NBLK_A, 256, 0, stream>>>(src, dst, scanT, ebuf);
    csrC_kernel<<<NB, 256, 0, stream>>>(ebuf, scanT, row_ptr, col, dinv);

    // --- layer 1: emb[N,32] -> bufB[N,64], relu ---
    mm_kernel<32, 64><<<NN / 16, 256, 0, stream>>>(emb, We1, dinv, hbuf);
    agg_kernel<64, true><<<(NN * 16 + 255) / 256, 256, 0, stream>>>(
        hbuf, row_ptr, col, dinv, be1, (float4*)bufB);

    // --- layer 2: bufB[N,64] -> z[N,32], relu ---
    mm_kernel<64, 32><<<NN / 32, 256, 0, stream>>>(bufB, We2, dinv, hbuf);
    agg_kernel<32, true><<<(NN * 8 + 255) / 256, 256, 0, stream>>>(
        hbuf, row_ptr, col, dinv, be2, (float4*)z);

    // --- layer 3: z[N,32] -> bufB[N,64], relu ---
    mm_kernel<32, 64><<<NN / 16, 256, 0, stream>>>(z, Wd1, dinv, hbuf);
    agg_kernel<64, true><<<(NN * 16 + 255) / 256, 256, 0, stream>>>(
        hbuf, row_ptr, col, dinv, bd1, (float4*)bufB);

    // --- layer 4: bufB[N,64] -> recon[N,128], no relu ---
    mm_kernel<64, 128><<<NN / 8, 256, 0, stream>>>(bufB, Wd2, dinv, hbuf);
    agg_kernel<128, false><<<(NN * 32 + 255) / 256, 256, 0, stream>>>(
        hbuf, row_ptr, col, dinv, bd2, (float4*)recon);
}

// Round 6
// 327.412 us; speedup vs baseline: 4.4367x; 1.2342x over previous
//
#include <hip/hip_runtime.h>
#include <hip/hip_fp16.h>

#define NN 100000
#define NE 1600000
#define NB 782            // dst buckets of 128 nodes: ceil(NN/128)
#define EPB 8192          // edges per block in bucket phases
#define NBLK_A 196        // ceil(NE/EPB)
#define SCNT (NB * NBLK_A)             // 153272 (divisible by 4)
#define SC_NB ((SCNT + 1023) / 1024)   // 150
#define CAP 4096          // bucket capacity for LDS staging (mean 2046, sd ~45)

// ---------------- CSR build: atomic-light bucketing ----------------

__global__ void bhistA_kernel(const int* __restrict__ dst, int* __restrict__ histT) {
    __shared__ int hist[NB];
    int t = threadIdx.x, b = blockIdx.x;
    for (int i = t; i < NB; i += 256) hist[i] = 0;
    __syncthreads();
    int e0 = b * EPB;
    for (int i = t; i < EPB; i += 256) {
        int e = e0 + i;
        if (e < NE) atomicAdd(&hist[dst[e] >> 7], 1);
    }
    __syncthreads();
    for (int i = t; i < NB; i += 256) histT[i * NBLK_A + b] = hist[i];
}

__global__ void scan1g_kernel(const int* __restrict__ in, int* __restrict__ out,
                              int* __restrict__ blkSum) {
    __shared__ int ts[256];
    int t = threadIdx.x, b = blockIdx.x;
    int base = b * 1024 + t * 4;
    int4 c = {0, 0, 0, 0};
    if (base < SCNT) c = *(const int4*)(in + base);
    int s = c.x + c.y + c.z + c.w;
    ts[t] = s;
    __syncthreads();
    for (int ofs = 1; ofs < 256; ofs <<= 1) {
        int v = (t >= ofs) ? ts[t - ofs] : 0;
        __syncthreads();
        ts[t] += v;
        __syncthreads();
    }
    if (t == 255) blkSum[b] = ts[255];
    int ex = ts[t] - s;
    if (base < SCNT) {
        int4 p;
        p.x = ex; p.y = ex + c.x; p.z = p.y + c.y; p.w = p.z + c.z;
        *(int4*)(out + base) = p;
    }
}

__global__ void scan2g_kernel(int* __restrict__ blkSum) {  // SC_NB <= 256
    __shared__ int ts[256];
    int t = threadIdx.x;
    int v = (t < SC_NB) ? blkSum[t] : 0;
    ts[t] = v;
    __syncthreads();
    for (int ofs = 1; ofs < 256; ofs <<= 1) {
        int u = (t >= ofs) ? ts[t - ofs] : 0;
        __syncthreads();
        ts[t] += u;
        __syncthreads();
    }
    if (t < SC_NB) blkSum[t] = ts[t] - v;
}

__global__ void scan3g_kernel(int* __restrict__ out, const int* __restrict__ blkSum) {
    int b = blockIdx.x;
    int base = b * 1024 + threadIdx.x * 4;
    int off = blkSum[b];
    if (base < SCNT) {
        int4 p = *(const int4*)(out + base);
        p.x += off; p.y += off; p.z += off; p.w += off;
        *(int4*)(out + base) = p;
    }
}

__global__ void bscatB_kernel(const int* __restrict__ src, const int* __restrict__ dst,
                              const int* __restrict__ scanT, int2* __restrict__ ebuf) {
    __shared__ int cur[NB];
    int t = threadIdx.x, b = blockIdx.x;
    for (int i = t; i < NB; i += 256) cur[i] = scanT[i * NBLK_A + b];
    __syncthreads();
    int e0 = b * EPB;
    for (int i = t; i < EPB; i += 256) {
        int e = e0 + i;
        if (e < NE) {
            int d = dst[e];
            int p = atomicAdd(&cur[d >> 7], 1);  // LDS atomic
            ebuf[p] = make_int2(src[e], d);
        }
    }
}

__global__ void csrC_kernel(const int2* __restrict__ ebuf, const int* __restrict__ scanT,
                            int* __restrict__ row_ptr, int* __restrict__ col,
                            float* __restrict__ dinv) {
    __shared__ int2 es[CAP];
    __shared__ int hist[128];
    __shared__ int ts[128];
    __shared__ int cur[128];
    int t = threadIdx.x, b = blockIdx.x;
    int base = scanT[b * NBLK_A];
    int end  = (b + 1 < NB) ? scanT[(b + 1) * NBLK_A] : NE;
    int cnt = end - base;
    if (t < 128) hist[t] = 0;
    __syncthreads();
    for (int i = t; i < cnt; i += 256) {
        int2 e = ebuf[base + i];
        if (i < CAP) es[i] = e;
        atomicAdd(&hist[e.y & 127], 1);
    }
    __syncthreads();
    if (t < 128) ts[t] = hist[t];
    __syncthreads();
    for (int ofs = 1; ofs < 128; ofs <<= 1) {
        int v = 0;
        if (t < 128 && t >= ofs) v = ts[t - ofs];
        __syncthreads();
        if (t < 128) ts[t] += v;
        __syncthreads();
    }
    if (t < 128) {
        int ex = ts[t] - hist[t];
        cur[t] = ex;
        int g = b * 128 + t;
        if (g < NN) {
            row_ptr[g] = base + ex;
            dinv[g] = rsqrtf((float)hist[t] + 1.0f);
        }
    }
    if (b == 0 && t == 0) row_ptr[NN] = NE;
    __syncthreads();
    for (int i = t; i < cnt; i += 256) {
        int2 e = (i < CAP) ? es[i] : ebuf[base + i];
        int r = atomicAdd(&cur[e.y & 127], 1);  // LDS atomic
        col[base + r] = e.x;
    }
}

// ---------------- helpers ----------------

__device__ inline float4 h4_to_f4(ushort4 u) {
    float4 r;
    r.x = __half2float(__ushort_as_half(u.x));
    r.y = __half2float(__ushort_as_half(u.y));
    r.z = __half2float(__ushort_as_half(u.z));
    r.w = __half2float(__ushort_as_half(u.w));
    return r;
}

__device__ inline ushort4 f4_to_h4(float4 v) {
    ushort4 o;
    o.x = __half_as_ushort(__float2half(v.x));
    o.y = __half_as_ushort(__float2half(v.y));
    o.z = __half_as_ushort(__float2half(v.z));
    o.w = __half_as_ushort(__float2half(v.w));
    return o;
}

// ---------------- per-layer kernels ----------------

// q[i,c] = fp16(dinv[i] * x[i,c])
template<int C>
__global__ void quant_kernel(const float4* __restrict__ x, const float* __restrict__ dinv,
                             ushort4* __restrict__ q) {
    constexpr int TPN = C / 4;
    int gid = blockIdx.x * blockDim.x + threadIdx.x;
    if (gid >= NN * TPN) return;
    int node = gid / TPN;
    float d = dinv[node];
    float4 v = x[gid];
    v.x *= d; v.y *= d; v.z *= d; v.w *= d;
    q[gid] = f4_to_h4(v);
}

// mmT: h[i,:] = fp16(dinv[i] * (x[i,:] @ W))   (transform-first staging, layer 2)
template<int IN, int OUT>
__global__ void mmT_kernel(const float* __restrict__ x, const float* __restrict__ W,
                           const float* __restrict__ dinv, ushort4* __restrict__ h) {
    constexpr int TPN = OUT / 4;
    constexpr int NPB = 256 / TPN;
    constexpr int XP  = IN + 1;
    __shared__ float4 Ws[IN * TPN];
    __shared__ float  xs[NPB * XP];

    int tid = threadIdx.x;
    const float4* W4 = (const float4*)W;
    for (int i = tid; i < IN * TPN; i += 256) Ws[i] = W4[i];
    int n0 = blockIdx.x * NPB;
    for (int i = tid; i < NPB * IN; i += 256) {
        int r = i / IN, cc = i & (IN - 1);
        xs[r * XP + cc] = x[(size_t)n0 * IN + i];
    }
    __syncthreads();

    int ln = tid / TPN, cg = tid % TPN;
    int node = n0 + ln;
    const float* xr = xs + ln * XP;
    float4 acc = {0.f, 0.f, 0.f, 0.f};
#pragma unroll
    for (int k = 0; k < IN; ++k) {
        float xv = xr[k];
        float4 w = Ws[k * TPN + cg];
        acc.x = fmaf(xv, w.x, acc.x);
        acc.y = fmaf(xv, w.y, acc.y);
        acc.z = fmaf(xv, w.z, acc.z);
        acc.w = fmaf(xv, w.w, acc.w);
    }
    float d = dinv[node];
    acc.x *= d; acc.y *= d; acc.z *= d; acc.w *= d;
    h[(size_t)node * TPN + cg] = f4_to_h4(acc);
}

// mmB: out[i,:] = (relu)(a[i,:] @ W + b); QUANT -> fp16(dinv * result) instead.
template<int IN, int OUT, bool RELU, bool QUANT>
__global__ void mmB_kernel(const float* __restrict__ a, const float* __restrict__ W,
                           const float* __restrict__ bias, const float* __restrict__ dinv,
                           float4* __restrict__ out, ushort4* __restrict__ qout) {
    constexpr int TPN = OUT / 4;
    constexpr int NPB = 256 / TPN;
    constexpr int XP  = IN + 1;
    __shared__ float4 Ws[IN * TPN];
    __shared__ float  xs[NPB * XP];

    int tid = threadIdx.x;
    const float4* W4 = (const float4*)W;
    for (int i = tid; i < IN * TPN; i += 256) Ws[i] = W4[i];
    int n0 = blockIdx.x * NPB;
    for (int i = tid; i < NPB * IN; i += 256) {
        int r = i / IN, cc = i & (IN - 1);
        xs[r * XP + cc] = a[(size_t)n0 * IN + i];
    }
    __syncthreads();

    int ln = tid / TPN, cg = tid % TPN;
    int node = n0 + ln;
    const float* xr = xs + ln * XP;
    float4 bb = ((const float4*)bias)[cg];
    float4 acc = bb;
#pragma unroll
    for (int k = 0; k < IN; ++k) {
        float xv = xr[k];
        float4 w = Ws[k * TPN + cg];
        acc.x = fmaf(xv, w.x, acc.x);
        acc.y = fmaf(xv, w.y, acc.y);
        acc.z = fmaf(xv, w.z, acc.z);
        acc.w = fmaf(xv, w.w, acc.w);
    }
    if (RELU) {
        acc.x = fmaxf(acc.x, 0.f); acc.y = fmaxf(acc.y, 0.f);
        acc.z = fmaxf(acc.z, 0.f); acc.w = fmaxf(acc.w, 0.f);
    }
    if (QUANT) {
        float d = dinv[node];
        float4 v = acc;
        v.x *= d; v.y *= d; v.z *= d; v.w *= d;
        qout[(size_t)node * TPN + cg] = f4_to_h4(v);
    } else {
        out[(size_t)node * TPN + cg] = acc;
    }
}

// agg: s = h[i] + sum_{j in in(i)} h[col[j]]  (fp16 gather, f32 accum)
// BIASRELU: r = relu(dinv*s + b)  else  r = dinv*s.
// WRITE_Q additionally writes fp16(dinv * r).
template<int C, bool BIASRELU, bool WRITE_Q>
__global__ void agg_kernel(const ushort4* __restrict__ h, const int* __restrict__ row_ptr,
                           const int* __restrict__ col, const float* __restrict__ dinv,
                           const float* __restrict__ b, float4* __restrict__ out,
                           ushort4* __restrict__ qout) {
    constexpr int TPN = C / 4;
    int gid = blockIdx.x * blockDim.x + threadIdx.x;
    int node = gid / TPN;
    int cg = gid % TPN;
    if (node >= NN) return;
    int beg = row_ptr[node];
    int end = row_ptr[node + 1];
    float4 sum = h4_to_f4(h[(size_t)node * TPN + cg]);
    for (int j = beg; j < end; ++j) {
        int s = col[j];
        float4 v = h4_to_f4(h[(size_t)s * TPN + cg]);
        sum.x += v.x; sum.y += v.y; sum.z += v.z; sum.w += v.w;
    }
    float d = dinv[node];
    float4 r;
    if (BIASRELU) {
        float4 bb = ((const float4*)b)[cg];
        r.x = fmaxf(fmaf(d, sum.x, bb.x), 0.f);
        r.y = fmaxf(fmaf(d, sum.y, bb.y), 0.f);
        r.z = fmaxf(fmaf(d, sum.z, bb.z), 0.f);
        r.w = fmaxf(fmaf(d, sum.w, bb.w), 0.f);
    } else {
        r.x = d * sum.x; r.y = d * sum.y; r.z = d * sum.z; r.w = d * sum.w;
    }
    out[(size_t)node * TPN + cg] = r;
    if (WRITE_Q) {
        float4 v = r;
        v.x *= d; v.y *= d; v.z *= d; v.w *= d;
        qout[(size_t)node * TPN + cg] = f4_to_h4(v);
    }
}

// ---------------- launch ----------------

extern "C" void kernel_launch(void* const* d_in, const int* in_sizes, int n_in,
                              void* d_out, int out_size, void* d_ws, size_t ws_size,
                              hipStream_t stream) {
    const int* ei = (const int*)d_in[0];
    const int* src = ei;
    const int* dst = ei + NE;
    const float* emb = (const float*)d_in[1];
    const float* We1 = (const float*)d_in[2]; const float* be1 = (const float*)d_in[3];
    const float* We2 = (const float*)d_in[4]; const float* be2 = (const float*)d_in[5];
    const float* Wd1 = (const float*)d_in[6]; const float* bd1 = (const float*)d_in[7];
    const float* Wd2 = (const float*)d_in[8]; const float* bd2 = (const float*)d_in[9];

    float* outp  = (float*)d_out;
    float* recon = outp;                      // [NN*128]
    float* z     = outp + (size_t)NN * 128;   // [NN*32]

    char* ws = (char*)d_ws;
    size_t off = 0;
    auto alloc = [&](size_t bytes) {
        void* p = ws + off;
        off += (bytes + 255) & ~(size_t)255;
        return p;
    };
    int*     row_ptr = (int*)    alloc((size_t)(NN + 1) * 4);
    int*     col     = (int*)    alloc((size_t)NE * 4);
    float*   dinv    = (float*)  alloc((size_t)NN * 4);
    int*     histT   = (int*)    alloc((size_t)SCNT * 4);
    int*     scanT   = (int*)    alloc((size_t)SCNT * 4);
    int*     blkSum  = (int*)    alloc((size_t)SC_NB * 4);
    void*    region1 = alloc((size_t)NE * 8);              // ebuf, later fA (NN*32*4 = 12.8MB <= 12.8MB)
    ushort4* qA      = (ushort4*)alloc((size_t)NN * 64 * 2);
    ushort4* qB      = (ushort4*)alloc((size_t)NN * 64 * 2);
    float*   fB      = (float*)  alloc((size_t)NN * 64 * 4);
    int2*    ebuf    = (int2*)region1;
    float*   fA      = (float*)region1;   // alive only after CSR build done
    (void)ws_size; (void)in_sizes; (void)n_in; (void)out_size;

    // --- CSR build (bucketed, no global atomics) ---
    bhistA_kernel<<<NBLK_A, 256, 0, stream>>>(dst, histT);
    scan1g_kernel<<<SC_NB, 256, 0, stream>>>(histT, scanT, blkSum);
    scan2g_kernel<<<1, 256, 0, stream>>>(blkSum);
    scan3g_kernel<<<SC_NB, 256, 0, stream>>>(scanT, blkSum);
    bscatB_kernel<<<NBLK_A, 256, 0, stream>>>(src, dst, scanT, ebuf);
    csrC_kernel<<<NB, 256, 0, stream>>>(ebuf, scanT, row_ptr, col, dinv);

    // --- layer 1 (agg-first): q1 = fp16(dinv*emb); a1 = dinv*(q1+Σ); x1 = relu(a1@We1+be1) ---
    quant_kernel<32><<<(NN * 8 + 255) / 256, 256, 0, stream>>>((const float4*)emb, dinv, qA);
    agg_kernel<32, false, false><<<(NN * 8 + 255) / 256, 256, 0, stream>>>(
        qA, row_ptr, col, dinv, nullptr, (float4*)fA, nullptr);
    mmB_kernel<32, 64, true, false><<<NN / 16, 256, 0, stream>>>(
        fA, We1, be1, dinv, (float4*)fB, nullptr);

    // --- layer 2 (transform-first): h2 = fp16(dinv*(x1@We2)); z = relu(dinv*(h2+Σ)+be2); q3 = fp16(dinv*z) ---
    mmT_kernel<64, 32><<<NN / 32, 256, 0, stream>>>(fB, We2, dinv, qB);
    agg_kernel<32, true, true><<<(NN * 8 + 255) / 256, 256, 0, stream>>>(
        qB, row_ptr, col, dinv, be2, (float4*)z, qA);

    // --- layer 3 (agg-first): a3 = dinv*(q3+Σ); q4 = fp16(dinv*relu(a3@Wd1+bd1)) ---
    agg_kernel<32, false, false><<<(NN * 8 + 255) / 256, 256, 0, stream>>>(
        qA, row_ptr, col, dinv, nullptr, (float4*)fA, nullptr);
    mmB_kernel<32, 64, true, true><<<NN / 16, 256, 0, stream>>>(
        fA, Wd1, bd1, dinv, nullptr, qB);

    // --- layer 4 (agg-first): a4 = dinv*(q4+Σ); recon = a4@Wd2+bd2 ---
    agg_kernel<64, false, false><<<(NN * 16 + 255) / 256, 256, 0, stream>>>(
        qB, row_ptr, col, dinv, nullptr, (float4*)fB, nullptr);
    mmB_kernel<64, 128, false, false><<<NN / 8, 256, 0, stream>>>(
        fB, Wd2, bd2, dinv, (float4*)recon, nullptr);
}

// Round 7
// 260.210 us; speedup vs baseline: 5.5826x; 1.2583x over previous
//
#include <hip/hip_runtime.h>
#include <hip/hip_fp16.h>

#define NN 100000
#define NE 1600000
#define NB 782            // dst buckets of 128 nodes: ceil(NN/128)
#define EPB 8192          // edges per block in bucket phases
#define NBLK_A 196        // ceil(NE/EPB)
#define SCNT (NB * NBLK_A)             // 153272 (divisible by 4)
#define SC_NB ((SCNT + 1023) / 1024)   // 150
#define CAP 4096          // bucket capacity for LDS staging (mean 2046, sd ~45)

// ---------------- CSR build: atomic-light bucketing ----------------

__global__ void bhistA_kernel(const int* __restrict__ dst, int* __restrict__ histT) {
    __shared__ int hist[NB];
    int t = threadIdx.x, b = blockIdx.x;
    for (int i = t; i < NB; i += 256) hist[i] = 0;
    __syncthreads();
    int e0 = b * EPB;
    for (int i = t; i < EPB; i += 256) {
        int e = e0 + i;
        if (e < NE) atomicAdd(&hist[dst[e] >> 7], 1);
    }
    __syncthreads();
    for (int i = t; i < NB; i += 256) histT[i * NBLK_A + b] = hist[i];
}

__global__ void scan1g_kernel(const int* __restrict__ in, int* __restrict__ out,
                              int* __restrict__ blkSum) {
    __shared__ int ts[256];
    int t = threadIdx.x, b = blockIdx.x;
    int base = b * 1024 + t * 4;
    int4 c = {0, 0, 0, 0};
    if (base < SCNT) c = *(const int4*)(in + base);
    int s = c.x + c.y + c.z + c.w;
    ts[t] = s;
    __syncthreads();
    for (int ofs = 1; ofs < 256; ofs <<= 1) {
        int v = (t >= ofs) ? ts[t - ofs] : 0;
        __syncthreads();
        ts[t] += v;
        __syncthreads();
    }
    if (t == 255) blkSum[b] = ts[255];
    int ex = ts[t] - s;
    if (base < SCNT) {
        int4 p;
        p.x = ex; p.y = ex + c.x; p.z = p.y + c.y; p.w = p.z + c.z;
        *(int4*)(out + base) = p;
    }
}

__global__ void scan2g_kernel(int* __restrict__ blkSum) {  // SC_NB <= 256
    __shared__ int ts[256];
    int t = threadIdx.x;
    int v = (t < SC_NB) ? blkSum[t] : 0;
    ts[t] = v;
    __syncthreads();
    for (int ofs = 1; ofs < 256; ofs <<= 1) {
        int u = (t >= ofs) ? ts[t - ofs] : 0;
        __syncthreads();
        ts[t] += u;
        __syncthreads();
    }
    if (t < SC_NB) blkSum[t] = ts[t] - v;
}

__global__ void scan3g_kernel(int* __restrict__ out, const int* __restrict__ blkSum) {
    int b = blockIdx.x;
    int base = b * 1024 + threadIdx.x * 4;
    int off = blkSum[b];
    if (base < SCNT) {
        int4 p = *(const int4*)(out + base);
        p.x += off; p.y += off; p.z += off; p.w += off;
        *(int4*)(out + base) = p;
    }
}

__global__ void bscatB_kernel(const int* __restrict__ src, const int* __restrict__ dst,
                              const int* __restrict__ scanT, int2* __restrict__ ebuf) {
    __shared__ int cur[NB];
    int t = threadIdx.x, b = blockIdx.x;
    for (int i = t; i < NB; i += 256) cur[i] = scanT[i * NBLK_A + b];
    __syncthreads();
    int e0 = b * EPB;
    for (int i = t; i < EPB; i += 256) {
        int e = e0 + i;
        if (e < NE) {
            int d = dst[e];
            int p = atomicAdd(&cur[d >> 7], 1);  // LDS atomic
            ebuf[p] = make_int2(src[e], d);
        }
    }
}

__global__ void csrC_kernel(const int2* __restrict__ ebuf, const int* __restrict__ scanT,
                            int* __restrict__ row_ptr, int* __restrict__ col,
                            float* __restrict__ dinv) {
    __shared__ int2 es[CAP];
    __shared__ int hist[128];
    __shared__ int ts[128];
    __shared__ int cur[128];
    int t = threadIdx.x, b = blockIdx.x;
    int base = scanT[b * NBLK_A];
    int end  = (b + 1 < NB) ? scanT[(b + 1) * NBLK_A] : NE;
    int cnt = end - base;
    if (t < 128) hist[t] = 0;
    __syncthreads();
    for (int i = t; i < cnt; i += 256) {
        int2 e = ebuf[base + i];
        if (i < CAP) es[i] = e;
        atomicAdd(&hist[e.y & 127], 1);
    }
    __syncthreads();
    if (t < 128) ts[t] = hist[t];
    __syncthreads();
    for (int ofs = 1; ofs < 128; ofs <<= 1) {
        int v = 0;
        if (t < 128 && t >= ofs) v = ts[t - ofs];
        __syncthreads();
        if (t < 128) ts[t] += v;
        __syncthreads();
    }
    if (t < 128) {
        int ex = ts[t] - hist[t];
        cur[t] = ex;
        int g = b * 128 + t;
        if (g < NN) {
            row_ptr[g] = base + ex;
            dinv[g] = rsqrtf((float)hist[t] + 1.0f);
        }
    }
    if (b == 0 && t == 0) row_ptr[NN] = NE;
    __syncthreads();
    for (int i = t; i < cnt; i += 256) {
        int2 e = (i < CAP) ? es[i] : ebuf[base + i];
        int r = atomicAdd(&cur[e.y & 127], 1);  // LDS atomic
        col[base + r] = e.x;
    }
}

// ---------------- helpers ----------------

__device__ inline ushort4 f4_to_h4(float4 v) {
    ushort4 o;
    o.x = __half_as_ushort(__float2half(v.x));
    o.y = __half_as_ushort(__float2half(v.y));
    o.z = __half_as_ushort(__float2half(v.z));
    o.w = __half_as_ushort(__float2half(v.w));
    return o;
}

// q[i,c] = fp16(dinv[i] * x[i,c])
template<int C>
__global__ void quant_kernel(const float4* __restrict__ x, const float* __restrict__ dinv,
                             ushort4* __restrict__ q) {
    constexpr int TPN = C / 4;
    int gid = blockIdx.x * blockDim.x + threadIdx.x;
    if (gid >= NN * TPN) return;
    int node = gid / TPN;
    float d = dinv[node];
    float4 v = x[gid];
    v.x *= d; v.y *= d; v.z *= d; v.w *= d;
    q[gid] = f4_to_h4(v);
}

// ---------------- register-tiled matmul ----------------
// Thread computes 4 rows x 4 cols. Rows strided by RG so x-reads are
// broadcast within a cg-group and bank-tiled across rg-groups.
// QUANT: write fp16(dinv * result); else write f32 result.
template<int IN, int OUT, bool RELU, bool HASBIAS, bool QUANT>
__global__ void mm_kernel(const float* __restrict__ x, const float* __restrict__ W,
                          const float* __restrict__ bias, const float* __restrict__ dinv,
                          float4* __restrict__ out, ushort4* __restrict__ qout) {
    constexpr int CG   = OUT / 4;      // col groups: 8,16,32
    constexpr int RG   = 256 / CG;     // row groups: 32,16,8
    constexpr int ROWS = RG * 4;       // rows per block: 128,64,32
    constexpr int P    = IN + 4;       // padded x pitch (floats, mult of 4)
    __shared__ float4 Ws[IN * CG];
    __shared__ float  xs[ROWS * P];

    int tid = threadIdx.x;
    const float4* W4 = (const float4*)W;
    for (int i = tid; i < IN * CG; i += 256) Ws[i] = W4[i];

    int n0 = blockIdx.x * ROWS;
    for (int i = tid; i < ROWS * IN; i += 256) {
        int r = i / IN, c = i & (IN - 1);
        size_t g = (size_t)n0 * IN + i;
        if (g < (size_t)NN * IN) xs[r * P + c] = x[g];
    }
    __syncthreads();

    int cg = tid % CG;
    int rg = tid / CG;

    float4 acc[4] = {{0,0,0,0},{0,0,0,0},{0,0,0,0},{0,0,0,0}};
#pragma unroll 2
    for (int k = 0; k < IN; k += 4) {
        float4 w0 = Ws[(k + 0) * CG + cg];
        float4 w1 = Ws[(k + 1) * CG + cg];
        float4 w2 = Ws[(k + 2) * CG + cg];
        float4 w3 = Ws[(k + 3) * CG + cg];
#pragma unroll
        for (int i = 0; i < 4; ++i) {
            float4 xq = *(const float4*)&xs[(i * RG + rg) * P + k];
            acc[i].x = fmaf(xq.x, w0.x, acc[i].x);
            acc[i].y = fmaf(xq.x, w0.y, acc[i].y);
            acc[i].z = fmaf(xq.x, w0.z, acc[i].z);
            acc[i].w = fmaf(xq.x, w0.w, acc[i].w);
            acc[i].x = fmaf(xq.y, w1.x, acc[i].x);
            acc[i].y = fmaf(xq.y, w1.y, acc[i].y);
            acc[i].z = fmaf(xq.y, w1.z, acc[i].z);
            acc[i].w = fmaf(xq.y, w1.w, acc[i].w);
            acc[i].x = fmaf(xq.z, w2.x, acc[i].x);
            acc[i].y = fmaf(xq.z, w2.y, acc[i].y);
            acc[i].z = fmaf(xq.z, w2.z, acc[i].z);
            acc[i].w = fmaf(xq.z, w2.w, acc[i].w);
            acc[i].x = fmaf(xq.w, w3.x, acc[i].x);
            acc[i].y = fmaf(xq.w, w3.y, acc[i].y);
            acc[i].z = fmaf(xq.w, w3.z, acc[i].z);
            acc[i].w = fmaf(xq.w, w3.w, acc[i].w);
        }
    }

    float4 bb = {0, 0, 0, 0};
    if (HASBIAS) bb = ((const float4*)bias)[cg];
#pragma unroll
    for (int i = 0; i < 4; ++i) {
        int node = n0 + i * RG + rg;
        if (node >= NN) continue;
        float4 r = acc[i];
        if (HASBIAS) { r.x += bb.x; r.y += bb.y; r.z += bb.z; r.w += bb.w; }
        if (RELU) {
            r.x = fmaxf(r.x, 0.f); r.y = fmaxf(r.y, 0.f);
            r.z = fmaxf(r.z, 0.f); r.w = fmaxf(r.w, 0.f);
        }
        if (QUANT) {
            float d = dinv[node];
            r.x *= d; r.y *= d; r.z *= d; r.w *= d;
            qout[(size_t)node * CG + cg] = f4_to_h4(r);
        } else {
            out[(size_t)node * CG + cg] = r;
        }
    }
}

// ---------------- aggregate (fp16 gather, f32 accum, 16B loads, 4x ILP) ----------------

__device__ inline void acc8(float* a, uint4 u) {
    const __half2* hp = (const __half2*)&u;
#pragma unroll
    for (int q = 0; q < 4; ++q) {
        float2 f = __half22float2(hp[q]);
        a[2 * q]     += f.x;
        a[2 * q + 1] += f.y;
    }
}

// s = h[i] + sum_j h[col[j]];  BIASRELU: r = relu(dinv*s+b) else r = dinv*s.
// WRITE_Q additionally writes fp16(dinv*r). Thread = (node, 8-channel group).
template<int C, bool BIASRELU, bool WRITE_Q>
__global__ void agg_kernel(const uint4* __restrict__ h, const int* __restrict__ row_ptr,
                           const int* __restrict__ col, const float* __restrict__ dinv,
                           const float* __restrict__ b, float4* __restrict__ out,
                           uint4* __restrict__ qout) {
    constexpr int TPN = C / 8;
    int gid = blockIdx.x * blockDim.x + threadIdx.x;
    int node = gid / TPN;
    int cg = gid % TPN;
    if (node >= NN) return;
    int beg = row_ptr[node];
    int end = row_ptr[node + 1];

    float a[8] = {0, 0, 0, 0, 0, 0, 0, 0};
    acc8(a, h[(size_t)node * TPN + cg]);  // self-loop term

    int j = beg;
    for (; j + 4 <= end; j += 4) {
        int s0 = col[j], s1 = col[j + 1], s2 = col[j + 2], s3 = col[j + 3];
        uint4 u0 = h[(size_t)s0 * TPN + cg];
        uint4 u1 = h[(size_t)s1 * TPN + cg];
        uint4 u2 = h[(size_t)s2 * TPN + cg];
        uint4 u3 = h[(size_t)s3 * TPN + cg];
        acc8(a, u0); acc8(a, u1); acc8(a, u2); acc8(a, u3);
    }
    for (; j < end; ++j) acc8(a, h[(size_t)col[j] * TPN + cg]);

    float d = dinv[node];
    float r[8];
    if (BIASRELU) {
        const float* bp = b + cg * 8;
#pragma unroll
        for (int q = 0; q < 8; ++q) r[q] = fmaxf(fmaf(d, a[q], bp[q]), 0.f);
    } else {
#pragma unroll
        for (int q = 0; q < 8; ++q) r[q] = d * a[q];
    }
    float4* op = out + (size_t)node * (C / 4) + cg * 2;
    op[0] = make_float4(r[0], r[1], r[2], r[3]);
    op[1] = make_float4(r[4], r[5], r[6], r[7]);
    if (WRITE_Q) {
        uint4 qv;
        __half2* qp = (__half2*)&qv;
#pragma unroll
        for (int q = 0; q < 4; ++q)
            qp[q] = __float22half2_rn(make_float2(r[2 * q] * d, r[2 * q + 1] * d));
        qout[(size_t)node * TPN + cg] = qv;
    }
}

// ---------------- launch ----------------

extern "C" void kernel_launch(void* const* d_in, const int* in_sizes, int n_in,
                              void* d_out, int out_size, void* d_ws, size_t ws_size,
                              hipStream_t stream) {
    const int* ei = (const int*)d_in[0];
    const int* src = ei;
    const int* dst = ei + NE;
    const float* emb = (const float*)d_in[1];
    const float* We1 = (const float*)d_in[2]; const float* be1 = (const float*)d_in[3];
    const float* We2 = (const float*)d_in[4]; const float* be2 = (const float*)d_in[5];
    const float* Wd1 = (const float*)d_in[6]; const float* bd1 = (const float*)d_in[7];
    const float* Wd2 = (const float*)d_in[8]; const float* bd2 = (const float*)d_in[9];

    float* outp  = (float*)d_out;
    float* recon = outp;                      // [NN*128]
    float* z     = outp + (size_t)NN * 128;   // [NN*32]

    char* ws = (char*)d_ws;
    size_t off = 0;
    auto alloc = [&](size_t bytes) {
        void* p = ws + off;
        off += (bytes + 255) & ~(size_t)255;
        return p;
    };
    int*     row_ptr = (int*)    alloc((size_t)(NN + 1) * 4);
    int*     col     = (int*)    alloc((size_t)NE * 4);
    float*   dinv    = (float*)  alloc((size_t)NN * 4);
    int*     histT   = (int*)    alloc((size_t)SCNT * 4);
    int*     scanT   = (int*)    alloc((size_t)SCNT * 4);
    int*     blkSum  = (int*)    alloc((size_t)SC_NB * 4);
    void*    region1 = alloc((size_t)NE * 8);              // ebuf, later fA (12.8MB)
    ushort4* qA      = (ushort4*)alloc((size_t)NN * 64 * 2);
    ushort4* qB      = (ushort4*)alloc((size_t)NN * 64 * 2);
    float*   fB      = (float*)  alloc((size_t)NN * 64 * 4);
    int2*    ebuf    = (int2*)region1;
    float*   fA      = (float*)region1;   // alive only after CSR build done
    (void)ws_size; (void)in_sizes; (void)n_in; (void)out_size;

    // --- CSR build (bucketed, no global atomics) ---
    bhistA_kernel<<<NBLK_A, 256, 0, stream>>>(dst, histT);
    scan1g_kernel<<<SC_NB, 256, 0, stream>>>(histT, scanT, blkSum);
    scan2g_kernel<<<1, 256, 0, stream>>>(blkSum);
    scan3g_kernel<<<SC_NB, 256, 0, stream>>>(scanT, blkSum);
    bscatB_kernel<<<NBLK_A, 256, 0, stream>>>(src, dst, scanT, ebuf);
    csrC_kernel<<<NB, 256, 0, stream>>>(ebuf, scanT, row_ptr, col, dinv);

    // --- layer 1 (agg-first): q1 = fp16(dinv*emb); a1 = dinv*(q1+Σ); x1 = relu(a1@We1+be1) ---
    quant_kernel<32><<<(NN * 8 + 255) / 256, 256, 0, stream>>>((const float4*)emb, dinv, qA);
    agg_kernel<32, false, false><<<(NN * 4 + 255) / 256, 256, 0, stream>>>(
        (const uint4*)qA, row_ptr, col, dinv, nullptr, (float4*)fA, nullptr);
    mm_kernel<32, 64, true, true, false><<<(NN + 63) / 64, 256, 0, stream>>>(
        fA, We1, be1, dinv, (float4*)fB, nullptr);

    // --- layer 2 (transform-first): h2 = fp16(dinv*(x1@We2)); z = relu(dinv*(h2+Σ)+be2); q3 = fp16(dinv*z) ---
    mm_kernel<64, 32, false, false, true><<<(NN + 127) / 128, 256, 0, stream>>>(
        fB, We2, nullptr, dinv, nullptr, qB);
    agg_kernel<32, true, true><<<(NN * 4 + 255) / 256, 256, 0, stream>>>(
        (const uint4*)qB, row_ptr, col, dinv, be2, (float4*)z, (uint4*)qA);

    // --- layer 3 (agg-first): a3 = dinv*(q3+Σ); q4 = fp16(dinv*relu(a3@Wd1+bd1)) ---
    agg_kernel<32, false, false><<<(NN * 4 + 255) / 256, 256, 0, stream>>>(
        (const uint4*)qA, row_ptr, col, dinv, nullptr, (float4*)fA, nullptr);
    mm_kernel<32, 64, true, true, true><<<(NN + 63) / 64, 256, 0, stream>>>(
        fA, Wd1, bd1, dinv, nullptr, qB);

    // --- layer 4 (agg-first): a4 = dinv*(q4+Σ); recon = a4@Wd2+bd2 ---
    agg_kernel<64, false, false><<<(NN * 8 + 255) / 256, 256, 0, stream>>>(
        (const uint4*)qB, row_ptr, col, dinv, nullptr, (float4*)fB, nullptr);
    mm_kernel<64, 128, false, true, false><<<(NN + 31) / 32, 256, 0, stream>>>(
        fB, Wd2, bd2, dinv, (float4*)recon, nullptr);
}

// Round 8
// 259.478 us; speedup vs baseline: 5.5983x; 1.0028x over previous
//
#include <hip/hip_runtime.h>
#include <hip/hip_fp16.h>

#define NN 100000
#define NE 1600000
#define NB 782            // dst buckets of 128 nodes: ceil(NN/128)
#define EPB 2048          // edges per block in bucket phases
#define NBLK_A 782        // ceil(NE/EPB) = 781.25 -> 782
#define SCNT (NB * NBLK_A)             // 611524 (divisible by 4)
#define SC_NB ((SCNT + 1023) / 1024)   // 598
#define CAP 4096          // bucket capacity for LDS staging (mean 2046, sd ~45)

// ---------------- CSR build: atomic-light bucketing ----------------

__global__ void bhistA_kernel(const int* __restrict__ dst, int* __restrict__ histT) {
    __shared__ int hist[NB];
    int t = threadIdx.x, b = blockIdx.x;
    for (int i = t; i < NB; i += 256) hist[i] = 0;
    __syncthreads();
    int e0 = b * EPB;
    for (int i = t; i < EPB; i += 256) {
        int e = e0 + i;
        if (e < NE) atomicAdd(&hist[dst[e] >> 7], 1);
    }
    __syncthreads();
    for (int i = t; i < NB; i += 256) histT[i * NBLK_A + b] = hist[i];
}

__global__ void scan1g_kernel(const int* __restrict__ in, int* __restrict__ out,
                              int* __restrict__ blkSum) {
    __shared__ int ts[256];
    int t = threadIdx.x, b = blockIdx.x;
    int base = b * 1024 + t * 4;
    int4 c = {0, 0, 0, 0};
    if (base < SCNT) c = *(const int4*)(in + base);
    int s = c.x + c.y + c.z + c.w;
    ts[t] = s;
    __syncthreads();
    for (int ofs = 1; ofs < 256; ofs <<= 1) {
        int v = (t >= ofs) ? ts[t - ofs] : 0;
        __syncthreads();
        ts[t] += v;
        __syncthreads();
    }
    if (t == 255) blkSum[b] = ts[255];
    int ex = ts[t] - s;
    if (base < SCNT) {
        int4 p;
        p.x = ex; p.y = ex + c.x; p.z = p.y + c.y; p.w = p.z + c.z;
        *(int4*)(out + base) = p;
    }
}

__global__ void scan2g_kernel(int* __restrict__ blkSum) {  // SC_NB <= 1024
    __shared__ int ts[1024];
    int t = threadIdx.x;
    int v = (t < SC_NB) ? blkSum[t] : 0;
    ts[t] = v;
    __syncthreads();
    for (int ofs = 1; ofs < 1024; ofs <<= 1) {
        int u = (t >= ofs) ? ts[t - ofs] : 0;
        __syncthreads();
        ts[t] += u;
        __syncthreads();
    }
    if (t < SC_NB) blkSum[t] = ts[t] - v;
}

__global__ void scan3g_kernel(int* __restrict__ out, const int* __restrict__ blkSum) {
    int b = blockIdx.x;
    int base = b * 1024 + threadIdx.x * 4;
    int off = blkSum[b];
    if (base < SCNT) {
        int4 p = *(const int4*)(out + base);
        p.x += off; p.y += off; p.z += off; p.w += off;
        *(int4*)(out + base) = p;
    }
}

// Scatter packed (src | local_dst<<20) into bucket segments; cursors in LDS.
__global__ void bscatB_kernel(const int* __restrict__ src, const int* __restrict__ dst,
                              const int* __restrict__ scanT, int* __restrict__ ebuf) {
    __shared__ int cur[NB];
    int t = threadIdx.x, b = blockIdx.x;
    for (int i = t; i < NB; i += 256) cur[i] = scanT[i * NBLK_A + b];
    __syncthreads();
    int e0 = b * EPB;
    for (int i = t; i < EPB; i += 256) {
        int e = e0 + i;
        if (e < NE) {
            int d = dst[e];
            int p = atomicAdd(&cur[d >> 7], 1);  // LDS atomic
            ebuf[p] = src[e] | ((d & 127) << 20);
        }
    }
}

// Per-bucket CSR finalize: stage packed edges in LDS, 128-bin hist+scan,
// contiguous col writes, row_ptr, fused dinv.
__global__ void csrC_kernel(const int* __restrict__ ebuf, const int* __restrict__ scanT,
                            int* __restrict__ row_ptr, int* __restrict__ col,
                            float* __restrict__ dinv) {
    __shared__ int es[CAP];
    __shared__ int hist[128];
    __shared__ int ts[128];
    __shared__ int cur[128];
    int t = threadIdx.x, b = blockIdx.x;
    int base = scanT[b * NBLK_A];
    int end  = (b + 1 < NB) ? scanT[(b + 1) * NBLK_A] : NE;
    int cnt = end - base;
    if (t < 128) hist[t] = 0;
    __syncthreads();
    for (int i = t; i < cnt; i += 256) {
        int e = ebuf[base + i];
        if (i < CAP) es[i] = e;
        atomicAdd(&hist[e >> 20], 1);
    }
    __syncthreads();
    if (t < 128) ts[t] = hist[t];
    __syncthreads();
    for (int ofs = 1; ofs < 128; ofs <<= 1) {
        int v = 0;
        if (t < 128 && t >= ofs) v = ts[t - ofs];
        __syncthreads();
        if (t < 128) ts[t] += v;
        __syncthreads();
    }
    if (t < 128) {
        int ex = ts[t] - hist[t];
        cur[t] = ex;
        int g = b * 128 + t;
        if (g < NN) {
            row_ptr[g] = base + ex;
            dinv[g] = rsqrtf((float)hist[t] + 1.0f);
        }
    }
    if (b == 0 && t == 0) row_ptr[NN] = NE;
    __syncthreads();
    for (int i = t; i < cnt; i += 256) {
        int e = (i < CAP) ? es[i] : ebuf[base + i];
        int r = atomicAdd(&cur[e >> 20], 1);  // LDS atomic
        col[base + r] = e & 0xFFFFF;
    }
}

// ---------------- helpers ----------------

__device__ inline ushort4 f4_to_h4(float4 v) {
    ushort4 o;
    o.x = __half_as_ushort(__float2half(v.x));
    o.y = __half_as_ushort(__float2half(v.y));
    o.z = __half_as_ushort(__float2half(v.z));
    o.w = __half_as_ushort(__float2half(v.w));
    return o;
}

// q[i,c] = fp16(dinv[i] * x[i,c])
template<int C>
__global__ void quant_kernel(const float4* __restrict__ x, const float* __restrict__ dinv,
                             ushort4* __restrict__ q) {
    constexpr int TPN = C / 4;
    int gid = blockIdx.x * blockDim.x + threadIdx.x;
    if (gid >= NN * TPN) return;
    int node = gid / TPN;
    float d = dinv[node];
    float4 v = x[gid];
    v.x *= d; v.y *= d; v.z *= d; v.w *= d;
    q[gid] = f4_to_h4(v);
}

// ---------------- register-tiled matmul ----------------
template<int IN, int OUT, bool RELU, bool HASBIAS, bool QUANT>
__global__ void mm_kernel(const float* __restrict__ x, const float* __restrict__ W,
                          const float* __restrict__ bias, const float* __restrict__ dinv,
                          float4* __restrict__ out, ushort4* __restrict__ qout) {
    constexpr int CG   = OUT / 4;      // col groups: 8,16,32
    constexpr int RG   = 256 / CG;     // row groups: 32,16,8
    constexpr int ROWS = RG * 4;       // rows per block: 128,64,32
    constexpr int P    = IN + 4;       // padded x pitch
    __shared__ float4 Ws[IN * CG];
    __shared__ float  xs[ROWS * P];

    int tid = threadIdx.x;
    const float4* W4 = (const float4*)W;
    for (int i = tid; i < IN * CG; i += 256) Ws[i] = W4[i];

    int n0 = blockIdx.x * ROWS;
    for (int i = tid; i < ROWS * IN; i += 256) {
        int r = i / IN, c = i & (IN - 1);
        size_t g = (size_t)n0 * IN + i;
        if (g < (size_t)NN * IN) xs[r * P + c] = x[g];
    }
    __syncthreads();

    int cg = tid % CG;
    int rg = tid / CG;

    float4 acc[4] = {{0,0,0,0},{0,0,0,0},{0,0,0,0},{0,0,0,0}};
#pragma unroll 2
    for (int k = 0; k < IN; k += 4) {
        float4 w0 = Ws[(k + 0) * CG + cg];
        float4 w1 = Ws[(k + 1) * CG + cg];
        float4 w2 = Ws[(k + 2) * CG + cg];
        float4 w3 = Ws[(k + 3) * CG + cg];
#pragma unroll
        for (int i = 0; i < 4; ++i) {
            float4 xq = *(const float4*)&xs[(i * RG + rg) * P + k];
            acc[i].x = fmaf(xq.x, w0.x, acc[i].x);
            acc[i].y = fmaf(xq.x, w0.y, acc[i].y);
            acc[i].z = fmaf(xq.x, w0.z, acc[i].z);
            acc[i].w = fmaf(xq.x, w0.w, acc[i].w);
            acc[i].x = fmaf(xq.y, w1.x, acc[i].x);
            acc[i].y = fmaf(xq.y, w1.y, acc[i].y);
            acc[i].z = fmaf(xq.y, w1.z, acc[i].z);
            acc[i].w = fmaf(xq.y, w1.w, acc[i].w);
            acc[i].x = fmaf(xq.z, w2.x, acc[i].x);
            acc[i].y = fmaf(xq.z, w2.y, acc[i].y);
            acc[i].z = fmaf(xq.z, w2.z, acc[i].z);
            acc[i].w = fmaf(xq.z, w2.w, acc[i].w);
            acc[i].x = fmaf(xq.w, w3.x, acc[i].x);
            acc[i].y = fmaf(xq.w, w3.y, acc[i].y);
            acc[i].z = fmaf(xq.w, w3.z, acc[i].z);
            acc[i].w = fmaf(xq.w, w3.w, acc[i].w);
        }
    }

    float4 bb = {0, 0, 0, 0};
    if (HASBIAS) bb = ((const float4*)bias)[cg];
#pragma unroll
    for (int i = 0; i < 4; ++i) {
        int node = n0 + i * RG + rg;
        if (node >= NN) continue;
        float4 r = acc[i];
        if (HASBIAS) { r.x += bb.x; r.y += bb.y; r.z += bb.z; r.w += bb.w; }
        if (RELU) {
            r.x = fmaxf(r.x, 0.f); r.y = fmaxf(r.y, 0.f);
            r.z = fmaxf(r.z, 0.f); r.w = fmaxf(r.w, 0.f);
        }
        if (QUANT) {
            float d = dinv[node];
            r.x *= d; r.y *= d; r.z *= d; r.w *= d;
            qout[(size_t)node * CG + cg] = f4_to_h4(r);
        } else {
            out[(size_t)node * CG + cg] = r;
        }
    }
}

// ---------------- aggregate (fp16 gather, f32 accum, 16B loads, 8x ILP) ----------------

__device__ inline void acc8(float* a, uint4 u) {
    const __half2* hp = (const __half2*)&u;
#pragma unroll
    for (int q = 0; q < 4; ++q) {
        float2 f = __half22float2(hp[q]);
        a[2 * q]     += f.x;
        a[2 * q + 1] += f.y;
    }
}

template<int C, bool BIASRELU, bool WRITE_Q>
__global__ void agg_kernel(const uint4* __restrict__ h, const int* __restrict__ row_ptr,
                           const int* __restrict__ col, const float* __restrict__ dinv,
                           const float* __restrict__ b, float4* __restrict__ out,
                           uint4* __restrict__ qout) {
    constexpr int TPN = C / 8;
    int gid = blockIdx.x * blockDim.x + threadIdx.x;
    int node = gid / TPN;
    int cg = gid % TPN;
    if (node >= NN) return;
    int beg = row_ptr[node];
    int end = row_ptr[node + 1];

    float a[8] = {0, 0, 0, 0, 0, 0, 0, 0};
    acc8(a, h[(size_t)node * TPN + cg]);  // self-loop term

    int j = beg;
    for (; j + 8 <= end; j += 8) {
        int s[8];
        uint4 u[8];
#pragma unroll
        for (int q = 0; q < 8; ++q) s[q] = col[j + q];
#pragma unroll
        for (int q = 0; q < 8; ++q) u[q] = h[(size_t)s[q] * TPN + cg];
#pragma unroll
        for (int q = 0; q < 8; ++q) acc8(a, u[q]);
    }
    for (; j + 4 <= end; j += 4) {
        int s0 = col[j], s1 = col[j + 1], s2 = col[j + 2], s3 = col[j + 3];
        uint4 u0 = h[(size_t)s0 * TPN + cg];
        uint4 u1 = h[(size_t)s1 * TPN + cg];
        uint4 u2 = h[(size_t)s2 * TPN + cg];
        uint4 u3 = h[(size_t)s3 * TPN + cg];
        acc8(a, u0); acc8(a, u1); acc8(a, u2); acc8(a, u3);
    }
    for (; j < end; ++j) acc8(a, h[(size_t)col[j] * TPN + cg]);

    float d = dinv[node];
    float r[8];
    if (BIASRELU) {
        const float* bp = b + cg * 8;
#pragma unroll
        for (int q = 0; q < 8; ++q) r[q] = fmaxf(fmaf(d, a[q], bp[q]), 0.f);
    } else {
#pragma unroll
        for (int q = 0; q < 8; ++q) r[q] = d * a[q];
    }
    float4* op = out + (size_t)node * (C / 4) + cg * 2;
    op[0] = make_float4(r[0], r[1], r[2], r[3]);
    op[1] = make_float4(r[4], r[5], r[6], r[7]);
    if (WRITE_Q) {
        uint4 qv;
        __half2* qp = (__half2*)&qv;
#pragma unroll
        for (int q = 0; q < 4; ++q)
            qp[q] = __float22half2_rn(make_float2(r[2 * q] * d, r[2 * q + 1] * d));
        qout[(size_t)node * TPN + cg] = qv;
    }
}

// ---------------- launch ----------------

extern "C" void kernel_launch(void* const* d_in, const int* in_sizes, int n_in,
                              void* d_out, int out_size, void* d_ws, size_t ws_size,
                              hipStream_t stream) {
    const int* ei = (const int*)d_in[0];
    const int* src = ei;
    const int* dst = ei + NE;
    const float* emb = (const float*)d_in[1];
    const float* We1 = (const float*)d_in[2]; const float* be1 = (const float*)d_in[3];
    const float* We2 = (const float*)d_in[4]; const float* be2 = (const float*)d_in[5];
    const float* Wd1 = (const float*)d_in[6]; const float* bd1 = (const float*)d_in[7];
    const float* Wd2 = (const float*)d_in[8]; const float* bd2 = (const float*)d_in[9];

    float* outp  = (float*)d_out;
    float* recon = outp;                      // [NN*128]
    float* z     = outp + (size_t)NN * 128;   // [NN*32]

    char* ws = (char*)d_ws;
    size_t off = 0;
    auto alloc = [&](size_t bytes) {
        void* p = ws + off;
        off += (bytes + 255) & ~(size_t)255;
        return p;
    };
    int*     row_ptr = (int*)    alloc((size_t)(NN + 1) * 4);
    int*     col     = (int*)    alloc((size_t)NE * 4);
    float*   dinv    = (float*)  alloc((size_t)NN * 4);
    int*     histT   = (int*)    alloc((size_t)SCNT * 4);
    int*     scanT   = (int*)    alloc((size_t)SCNT * 4);
    int*     blkSum  = (int*)    alloc((size_t)SC_NB * 4);
    void*    region1 = alloc((size_t)NN * 32 * 4);         // ebuf (NE*4) / fA (NN*32*4), both 12.8MB... ebuf=6.4MB fits
    ushort4* qA      = (ushort4*)alloc((size_t)NN * 64 * 2);
    ushort4* qB      = (ushort4*)alloc((size_t)NN * 64 * 2);
    float*   fB      = (float*)  alloc((size_t)NN * 64 * 4);
    int*     ebuf    = (int*)region1;
    float*   fA      = (float*)region1;   // alive only after CSR build done
    (void)ws_size; (void)in_sizes; (void)n_in; (void)out_size;

    // --- CSR build (bucketed, no global atomics) ---
    bhistA_kernel<<<NBLK_A, 256, 0, stream>>>(dst, histT);
    scan1g_kernel<<<SC_NB, 256, 0, stream>>>(histT, scanT, blkSum);
    scan2g_kernel<<<1, 1024, 0, stream>>>(blkSum);
    scan3g_kernel<<<SC_NB, 256, 0, stream>>>(scanT, blkSum);
    bscatB_kernel<<<NBLK_A, 256, 0, stream>>>(src, dst, scanT, ebuf);
    csrC_kernel<<<NB, 256, 0, stream>>>(ebuf, scanT, row_ptr, col, dinv);

    // --- layer 1 (agg-first): q1 = fp16(dinv*emb); a1 = dinv*(q1+Σ); x1 = relu(a1@We1+be1) ---
    quant_kernel<32><<<(NN * 8 + 255) / 256, 256, 0, stream>>>((const float4*)emb, dinv, qA);
    agg_kernel<32, false, false><<<(NN * 4 + 255) / 256, 256, 0, stream>>>(
        (const uint4*)qA, row_ptr, col, dinv, nullptr, (float4*)fA, nullptr);
    mm_kernel<32, 64, true, true, false><<<(NN + 63) / 64, 256, 0, stream>>>(
        fA, We1, be1, dinv, (float4*)fB, nullptr);

    // --- layer 2 (transform-first): h2 = fp16(dinv*(x1@We2)); z = relu(dinv*(h2+Σ)+be2); q3 = fp16(dinv*z) ---
    mm_kernel<64, 32, false, false, true><<<(NN + 127) / 128, 256, 0, stream>>>(
        fB, We2, nullptr, dinv, nullptr, qB);
    agg_kernel<32, true, true><<<(NN * 4 + 255) / 256, 256, 0, stream>>>(
        (const uint4*)qB, row_ptr, col, dinv, be2, (float4*)z, (uint4*)qA);

    // --- layer 3 (agg-first): a3 = dinv*(q3+Σ); q4 = fp16(dinv*relu(a3@Wd1+bd1)) ---
    agg_kernel<32, false, false><<<(NN * 4 + 255) / 256, 256, 0, stream>>>(
        (const uint4*)qA, row_ptr, col, dinv, nullptr, (float4*)fA, nullptr);
    mm_kernel<32, 64, true, true, true><<<(NN + 63) / 64, 256, 0, stream>>>(
        fA, Wd1, bd1, dinv, nullptr, qB);

    // --- layer 4 (agg-first): a4 = dinv*(q4+Σ); recon = a4@Wd2+bd2 ---
    agg_kernel<64, false, false><<<(NN * 8 + 255) / 256, 256, 0, stream>>>(
        (const uint4*)qB, row_ptr, col, dinv, nullptr, (float4*)fB, nullptr);
    mm_kernel<64, 128, false, true, false><<<(NN + 31) / 32, 256, 0, stream>>>(
        fB, Wd2, bd2, dinv, (float4*)recon, nullptr);
}